// Round 7
// baseline (2706.110 us; speedup 1.0000x reference)
//
#include <hip/hip_runtime.h>
#include <math.h>

// ---------------- types ----------------
typedef _Float16 f16;
typedef _Float16 f16x8 __attribute__((ext_vector_type(8)));
typedef float f32x4 __attribute__((ext_vector_type(4)));
typedef unsigned int u32;
typedef u32 u32x4 __attribute__((ext_vector_type(4)));

#define DEV static __device__ __forceinline__

DEV float sigm(float x)  { return 1.0f / (1.0f + __expf(-x)); }
DEV float tanhfast(float x) { return 2.0f / (1.0f + __expf(-2.0f * x)) - 1.0f; }

// async global->LDS, 16B per lane (dest must be wave-uniform base + lane*16)
DEV void gld16(const void* g, void* l) {
  __builtin_amdgcn_global_load_lds((const __attribute__((address_space(1))) void*)g,
                                   (__attribute__((address_space(3))) void*)l, 16, 0, 0);
}

// ---------------- problem constants ----------------
// B=256 V=50 N=32 D=128 H=384 L=12 CS=10 ND=4096 G=1560 OUT=128
#define GP 1664   // padded G (13*128) — XK gemm N and XKh row stride
#define KH 3840   // H*CS (conv gemm K)
#define KO 19200  // V*H  (out gemm K)
#define ZSPLIT 40 // out gemm K-split (19200/40 = 480 = 15*32, exact)
#define XOLN 1668 // fused-recur xol row stride (f32; 1668%32=4 -> bank-spread)
#define HPAD 392  // fused-recur hbuf row stride (f16; 784B -> 2-way free)
// LDS: xol 16*1668*4 + hbuf 16*392*2 + svl 1664*4 + fm/im 2*192*4
#define FUSED_LDS (106752 + 12544 + 6656 + 1536)

// ---------------- workspace layout (bytes) ----------------
static constexpr size_t OFF_OPART = 0;                       // out partials 40*32768*4 = 5.24MB
static constexpr size_t OFF_WK    = 104857600;               // 13631488
static constexpr size_t OFF_XK    = OFF_WK + 13631488;       // XKh f16 42598400
// aliases of the XK region (XKh dead after k_recur):
static constexpr size_t OFF_MLH   = OFF_XK;                  // mlh_h f16 9830400
static constexpr size_t OFF_S1    = OFF_XK + 9830400;        // s1h f16 3276800
static constexpr size_t OFF_TH    = OFF_XK + 13107200;       // theme f32 19660800
static constexpr size_t OFF_CV    = OFF_XK + 32768000;       // conv partials 2x19660800 (ends +72089600)
static constexpr size_t OFF_SWP   = OFF_XK + 72089600;       // swp f16 98304 (> XKh end)
static constexpr size_t OFF_RWP2  = OFF_XK + 72187904;       // rwp2 f16 98304
static constexpr size_t OFF_SBP   = OFF_XK + 72286208;       // sbp f32 512
static constexpr size_t OFF_RW    = OFF_XK + 85196800;       // RWn f16 pack 1277952 (slot 1474560)
static constexpr size_t OFF_SV    = OFF_RW + 1474560;        // Sv f32 6656 (pad 8192)
static constexpr size_t OFF_BAR   = OFF_SV + 8192;           // (legacy bar region, unused by fused recur)
static constexpr size_t OFF_BIASC = OFF_BAR + 32768;         // 8192
static constexpr size_t OFF_HALL  = OFF_BIASC + 8192;        // h_all f16 9830400
static constexpr size_t OFF_LD    = OFF_HALL + 9830400;      // 512000
static constexpr size_t OFF_WC2   = OFF_LD + 512000;         // 2949120
static constexpr size_t OFF_RNN   = OFF_WC2 + 2949120;       // 9830400
static constexpr size_t OFF_OUTW  = OFF_RNN + 9830400;       // 4915200
static constexpr size_t OFF_EH    = OFF_OUTW + 4915200;      // embed f16 2560256

// ---------------- kernels ----------------

// kernel_w (1560 x 4097) -> Wk_f16 (1664 x 4096, zero-padded rows); biasc = kb+rb (padded 1664)
__global__ __launch_bounds__(256) void k_prep_wk(const float* __restrict__ kw,
                                                 const float* __restrict__ kb,
                                                 const float* __restrict__ rb,
                                                 f16* __restrict__ Wk,
                                                 float* __restrict__ biasc) {
  long i = (long)blockIdx.x * 256 + threadIdx.x;
  if (i < 1664L * 4096) {
    int nn = (int)(i >> 12);
    int k  = (int)(i & 4095);
    float v = (nn < 1560) ? kw[(long)nn * 4097 + k] : 0.0f;
    Wk[i] = (f16)v;
  }
  if (i < 1664) biasc[i] = (i < 1560) ? (kb[i] + rb[i]) : 0.0f;
}

// merged small prep: [0,180) RWn pack+Sv+bar, [180,276) scale pack, [276,3156) conv_w pack,
// [3156,7956) out_w cvt, [7956,10457) embed cvt
// RWn pack (fused-recur register fragments): chunk i < 79872 (16 waves x 78
// frags x 64 lanes of 8 f16). wave w: col-set cs=w>>1 (13 col-frags of 16),
// k-half kh=w&1 (6 k-frags of 32). frag f = j*6+i. lane (q=lane>>4, r16):
// col = cs*208 + j*16 + r16, k = (kh*6+i)*32 + q*8 .. +8. Mirrors the proven
// Bs fragment pattern (B[col][k], 8 consecutive k per lane).
__global__ __launch_bounds__(512) void k_prep_misc(const float* __restrict__ rw,
                                                   const float* __restrict__ kw,
                                                   const float* __restrict__ sw,
                                                   const float* __restrict__ sb,
                                                   const float* __restrict__ rw2,
                                                   const float* __restrict__ cw,
                                                   const float* __restrict__ ow,
                                                   const float* __restrict__ embed,
                                                   f16* __restrict__ RWn,
                                                   float* __restrict__ Sv,
                                                   int* __restrict__ bar,
                                                   f16* __restrict__ swp,
                                                   float* __restrict__ sbp,
                                                   f16* __restrict__ rwp2,
                                                   f16* __restrict__ Wc2,
                                                   f16* __restrict__ outw,
                                                   f16* __restrict__ Eh) {
  const int blk = blockIdx.x, tid = threadIdx.x;
  if (blk < 180) {
    int i = blk * 512 + tid;                 // 79872 chunks of 8 halfs
    if (i < 79872) {
      int w2   = i / 4992;
      int rem  = i - w2 * 4992;
      int f    = rem >> 6;
      int lane = rem & 63;
      int col  = (w2 >> 1) * 208 + (f / 6) * 16 + (lane & 15);
      int kk   = ((w2 & 1) * 6 + (f % 6)) * 32 + ((lane >> 4) << 3);
      f16x8 o;
      if (col < 1560) {
        const float* s = rw + (long)col * 385 + kk;
#pragma unroll
        for (int e = 0; e < 8; ++e) o[e] = (f16)s[e];
      } else {
#pragma unroll
        for (int e = 0; e < 8; ++e) o[e] = (f16)0.0f;
      }
      *(f16x8*)(RWn + (long)i * 8) = o;
    }
    if (i < 1664)
      Sv[i] = (i < 1560) ? (rw[(long)i * 385 + 384] + kw[(long)i * 4097 + 4096]) : 0.0f;
    if (i < 8192) bar[i] = 0;
  } else if (blk < 276) {
    int i = (blk - 180) * 512 + tid;         // 49152
    if (i < 128 * 384) {
      int o = i / 384, k = i - o * 384;
      swp[i] = (f16)((o < 64) ? sw[o * 384 + k] : 0.0f);
      int o2 = i >> 7, k2 = i & 127;
      rwp2[i] = (f16)((k2 < 64) ? rw2[o2 * 64 + k2] : 0.0f);
    }
    if (i < 128) sbp[i] = (i < 64) ? sb[i] : 0.0f;
  } else if (blk < 3156) {
    int i = (blk - 276) * 512 + tid;         // 384*3840 = 1474560
    if (i < 384 * 3840) {
      int o = i / 3840;
      int c = i - o * 3840;
      int j = c / 384;
      int h = c - j * 384;
      Wc2[i] = (f16)cw[((long)o * 384 + h) * 10 + j];
    }
  } else if (blk < 7956) {
    long i = (long)(blk - 3156) * 512 + tid; // 2457600
    if (i < 128L * KO) outw[i] = (f16)ow[i];
  } else {
    long i = (long)(blk - 7956) * 512 + tid; // 1280128
    if (i < 10001L * 128) Eh[i] = (f16)embed[i];
  }
}

// XKh = f16( gather(embed_h, ids) @ Wk^T + biasc ).
// v4: BK=64 via dual 32-K sub-tile LDS buffers; bijective XCD chunk-swizzle.
__global__ __launch_bounds__(256) void k_gemm_emb(const int* __restrict__ ids,  // (12800,32)
                                                  const f16* __restrict__ Eh,  // (10001,128)
                                                  const f16* __restrict__ W,   // (1664,4096)
                                                  f16* __restrict__ C,         // (12800,GP)
                                                  const float* __restrict__ bias) {
  __shared__ __align__(16) f16 As0[128 * 32];
  __shared__ __align__(16) f16 As1[128 * 32];
  __shared__ __align__(16) f16 Bs0[128 * 32];
  __shared__ __align__(16) f16 Bs1[128 * 32];
  const int tid = threadIdx.x;
  // nwg = 100*13 = 1300; q = 162, r = 4; xcd = W0&7 gets chunk of q(+1) wgids
  const int W0  = blockIdx.y * 100 + blockIdx.x;
  const int xcd = W0 & 7, idx = W0 >> 3;
  const int nw  = (xcd < 4) ? (xcd * 163 + idx) : (652 + (xcd - 4) * 162 + idx);
  const int bx  = nw % 100, by = nw / 100;
  const long rowA0 = (long)bx * 128;
  const long rowB0 = (long)by * 128;
  const int w = tid >> 6, lane = tid & 63;
  const int q = lane >> 4, r16 = lane & 15;
  const int wr = w >> 1, wc = w & 1;
  f32x4 acc[4][4] = {};
  const int srow = tid >> 2;
  const int scol = (tid & 3) * 8;
  const int* idr0 = ids + (rowA0 + srow) * 32;
  const int* idr1 = ids + (rowA0 + srow + 64) * 32;
  const f16* gB0 = W + (rowB0 + srow) * 4096L + scol;
  const f16* gB1 = gB0 + 64L * 4096;
  f16* lA0 = As0 + tid * 8;
  f16* lA1 = As1 + tid * 8;
  f16* lB0 = Bs0 + tid * 8;
  f16* lB1 = Bs1 + tid * 8;
  int cur0 = idr0[0], cur1 = idr1[0];
  for (int n = 0; n < 32; ++n) {
    int nx0 = 0, nx1 = 0;
    if (n < 31) { nx0 = idr0[n + 1]; nx1 = idr1[n + 1]; }
#pragma unroll
    for (int kk = 0; kk < 2; ++kk) {
      const int k0 = n * 128 + kk * 64;
      const int d = kk * 64 + scol;
      __syncthreads();
      gld16(Eh + (size_t)cur0 * 128 + d,      lA0);
      gld16(Eh + (size_t)cur1 * 128 + d,      lA0 + 2048);
      gld16(Eh + (size_t)cur0 * 128 + d + 32, lA1);
      gld16(Eh + (size_t)cur1 * 128 + d + 32, lA1 + 2048);
      gld16(gB0 + k0,      lB0);
      gld16(gB1 + k0,      lB0 + 2048);
      gld16(gB0 + k0 + 32, lB1);
      gld16(gB1 + k0 + 32, lB1 + 2048);
      __syncthreads();
      f16x8 af[4], bfr[4];
#pragma unroll
      for (int i = 0; i < 4; i++) {
        af[i]  = *(const f16x8*)&As0[(wr * 64 + i * 16 + r16) * 32 + q * 8];
        bfr[i] = *(const f16x8*)&Bs0[(wc * 64 + i * 16 + r16) * 32 + q * 8];
      }
#pragma unroll
      for (int i = 0; i < 4; i++)
#pragma unroll
        for (int j = 0; j < 4; j++)
          acc[i][j] = __builtin_amdgcn_mfma_f32_16x16x32_f16(af[i], bfr[j], acc[i][j], 0, 0, 0);
#pragma unroll
      for (int i = 0; i < 4; i++) {
        af[i]  = *(const f16x8*)&As1[(wr * 64 + i * 16 + r16) * 32 + q * 8];
        bfr[i] = *(const f16x8*)&Bs1[(wc * 64 + i * 16 + r16) * 32 + q * 8];
      }
#pragma unroll
      for (int i = 0; i < 4; i++)
#pragma unroll
        for (int j = 0; j < 4; j++)
          acc[i][j] = __builtin_amdgcn_mfma_f32_16x16x32_f16(af[i], bfr[j], acc[i][j], 0, 0, 0);
    }
    cur0 = nx0; cur1 = nx1;
  }
#pragma unroll
  for (int i = 0; i < 4; i++)
#pragma unroll
    for (int j = 0; j < 4; j++) {
      long row = rowA0 + wr * 64 + i * 16 + q * 4;
      long col = rowB0 + wc * 64 + j * 16 + r16;
      float bv = bias[col];
#pragma unroll
      for (int r = 0; r < 4; r++)
        C[(row + r) * (long)GP + col] = (f16)(acc[i][j][r] + bv);
    }
}

// conv GEMM with lh fused into A-staging
__global__ __launch_bounds__(256) void k_gemm_conv(const float* __restrict__ ld,   // (12800,10)
                                                   const f16* __restrict__ h_all, // (50,256,384)
                                                   const f16* __restrict__ W,     // Wc2 (384,3840)
                                                   float* __restrict__ C) {
  __shared__ __align__(16) f16 As[128 * 32];
  __shared__ __align__(16) f16 Bs[128 * 32];
  const int tid = threadIdx.x;
  const long rowA0 = (long)blockIdx.x * 128;
  const long rowB0 = (long)blockIdx.y * 128;
  const int ks = blockIdx.z * 1920;
  const long zoff = (long)blockIdx.z * (12800L * 384);
  const int w = tid >> 6, lane = tid & 63;
  const int q = lane >> 4, r16 = lane & 15;
  const int wr = w >> 1, wc = w & 1;
  f32x4 acc[4][4] = {};
  const int srow = tid >> 2;
  const int scol = (tid & 3) * 8;
  const int row0 = (int)rowA0 + srow, row1 = row0 + 64;
  const int b0r = row0 / 50, t0r = row0 - b0r * 50;
  const int b1r = row1 / 50, t1r = row1 - b1r * 50;
  const f16* gB0 = W + (rowB0 + srow) * (long)KH + ks + scol;
  const f16* gB1 = gB0 + 64L * KH;
  f16* lB = Bs + tid * 8;
  for (int k0 = 0; k0 < 1920; k0 += 32) {
    const int col0 = ks + k0;
    const int j = col0 / 384;
    const int hh = col0 - j * 384 + scol;
    const int s0 = t0r - 9 + j, s1 = t1r - 9 + j;
    __syncthreads();
    gld16(gB0 + k0, lB);
    gld16(gB1 + k0, lB + 2048);
    f16x8 a0v = {}, a1v = {};
    if (s0 >= 0) {
      const float lv = ld[row0 * 10 + j];
      f16x8 hv = *(const f16x8*)(h_all + ((size_t)s0 * 256 + b0r) * 384 + hh);
#pragma unroll
      for (int e = 0; e < 8; ++e) a0v[e] = (f16)((float)hv[e] * lv);
    }
    if (s1 >= 0) {
      const float lv = ld[row1 * 10 + j];
      f16x8 hv = *(const f16x8*)(h_all + ((size_t)s1 * 256 + b1r) * 384 + hh);
#pragma unroll
      for (int e = 0; e < 8; ++e) a1v[e] = (f16)((float)hv[e] * lv);
    }
    *(f16x8*)&As[srow * 32 + scol] = a0v;
    *(f16x8*)&As[(srow + 64) * 32 + scol] = a1v;
    __syncthreads();
    f16x8 af[4], bfr[4];
#pragma unroll
    for (int i = 0; i < 4; i++) {
      af[i]  = *(const f16x8*)&As[(wr * 64 + i * 16 + r16) * 32 + q * 8];
      bfr[i] = *(const f16x8*)&Bs[(wc * 64 + i * 16 + r16) * 32 + q * 8];
    }
#pragma unroll
    for (int i = 0; i < 4; i++)
#pragma unroll
      for (int j2 = 0; j2 < 4; j2++)
        acc[i][j2] = __builtin_amdgcn_mfma_f32_16x16x32_f16(af[i], bfr[j2], acc[i][j2], 0, 0, 0);
  }
#pragma unroll
  for (int i = 0; i < 4; i++)
#pragma unroll
    for (int j2 = 0; j2 < 4; j2++) {
      long row = rowA0 + wr * 64 + i * 16 + q * 4;
      long col = rowB0 + wc * 64 + j2 * 16 + r16;
#pragma unroll
      for (int r = 0; r < 4; r++)
        C[(row + r) * 384L + col + zoff] = acc[i][j2][r];
    }
}

// C = A(M x K) * W(N x K)^T (+bias[col]); m97-style global_load_lds staging.
__global__ __launch_bounds__(256) void k_gemm_bt(const f16* __restrict__ A,
                                                 const f16* __restrict__ W,
                                                 void* __restrict__ Cv,
                                                 const float* __restrict__ bias,
                                                 int N, int K, int kLen, int act) {
  __shared__ __align__(16) f16 As[128 * 32];
  __shared__ __align__(16) f16 Bs[128 * 32];
  const int tid = threadIdx.x;
  const long rowA0 = (long)blockIdx.x * 128;
  const long rowB0 = (long)blockIdx.y * 128;
  const long ks = (long)blockIdx.z * kLen;
  const long zoff = (long)blockIdx.z * ((long)gridDim.x * 128 * N);
  const int w = tid >> 6, lane = tid & 63;
  const int q = lane >> 4, r16 = lane & 15;
  const int wr = w >> 1, wc = w & 1;
  f32x4 acc[4][4] = {};
  const int srow = tid >> 2;
  const int scol = (tid & 3) * 8;
  const f16* gA0 = A + (rowA0 + srow) * (long)K + ks + scol;
  const f16* gA1 = gA0 + 64L * K;
  const f16* gB0 = W + (rowB0 + srow) * (long)K + ks + scol;
  const f16* gB1 = gB0 + 64L * K;
  f16* lA = As + tid * 8;
  f16* lB = Bs + tid * 8;
  for (int k0 = 0; k0 < kLen; k0 += 32) {
    __syncthreads();
    gld16(gA0 + k0, lA);
    gld16(gA1 + k0, lA + 2048);
    gld16(gB0 + k0, lB);
    gld16(gB1 + k0, lB + 2048);
    __syncthreads();
    f16x8 af[4], bfr[4];
#pragma unroll
    for (int i = 0; i < 4; i++) {
      af[i]  = *(const f16x8*)&As[(wr * 64 + i * 16 + r16) * 32 + q * 8];
      bfr[i] = *(const f16x8*)&Bs[(wc * 64 + i * 16 + r16) * 32 + q * 8];
    }
#pragma unroll
    for (int i = 0; i < 4; i++)
#pragma unroll
      for (int j = 0; j < 4; j++)
        acc[i][j] = __builtin_amdgcn_mfma_f32_16x16x32_f16(af[i], bfr[j], acc[i][j], 0, 0, 0);
  }
#pragma unroll
  for (int i = 0; i < 4; i++)
#pragma unroll
    for (int j = 0; j < 4; j++) {
      long row = rowA0 + wr * 64 + i * 16 + q * 4;
      long col = rowB0 + wc * 64 + j * 16 + r16;
      float bv = bias ? bias[col] : 0.0f;
#pragma unroll
      for (int r = 0; r < 4; r++) {
        float v = acc[i][j][r] + bv;
        long off = (row + r) * (long)N + col + zoff;
        if (act == 0)      ((float*)Cv)[off] = v;
        else if (act == 1) ((f16*)Cv)[off]   = (f16)v;
        else if (act == 2) ((f16*)Cv)[off]   = (f16)fmaxf(v, 0.0f);
        else               ((float*)Cv)[off] = sigm(v);
      }
    }
}

// ---------------------------------------------------------------------------
// Fused recurrence v8: 16 INDEPENDENT blocks (one per 16-batch group), 1024
// threads (16 waves). The entire rec_w (1.2 MB f16) is REGISTER-STATIONARY:
// wave w = (col-set cs = w>>1, k-half kh = w&1) holds 13 col-frags x 6 k-frags
// = 78 f16x8 = 312 VGPR of B-fragments. h lives in LDS. NO inter-block
// communication: no flags, no polls, no sc0sc1, no coop launch, no drain.
// Per step: P1 MFMA (1248/block) -> xol (k-half0 '='), BAR, P2 k-half1 '+=',
// BAR, P3 cumax softmax (192 threads) -> fm/im LDS + dists, BAR, P4 gate math
// (6 ch/thread, creg in regs) -> hbuf LDS + plain coalesced hall store, BAR.
// XK/bias and time*Sv are added at gate consumption (xk prefetched into regs
// at step start, hidden under MFMA; Sv staged in LDS).
// Replaces the 353 us 192-block flag-protocol kernel (R5 lesson: the cross-
// block LLC handoff is the floor of that design; this design removes it).
// ---------------------------------------------------------------------------
__global__ __launch_bounds__(1024, 1)
void k_recur_fused(const f16* __restrict__ XKh,
                   const f16* __restrict__ RWn,
                   const float* __restrict__ Sv,
                   const float* __restrict__ timep,
                   f16* __restrict__ hall,
                   float* __restrict__ dists) {
  extern __shared__ char smem[];
  float* xol  = (float*)smem;                            // [16][XOLN]
  f16*   hbuf = (f16*)(smem + 106752);                   // [16][HPAD]
  float* svl  = (float*)(smem + 106752 + 12544);         // [1664]
  float* fml  = (float*)(smem + 106752 + 12544 + 6656);  // [16][12]
  float* iml  = fml + 192;                               // [16][12]
  const int tid = threadIdx.x;
  const int b0 = blockIdx.x * 16;
  const int w = tid >> 6, lane = tid & 63;
  const int q = lane >> 4, r16 = lane & 15;
  const int cs = w >> 1, kh = w & 1;

  // wave-stationary weights: 78 f16x8 fragments (fully static indexing)
  f16x8 wv[78];
  {
    const f16* src = RWn + ((size_t)w * 4992 + lane) * 8;
#pragma unroll
    for (int f = 0; f < 78; ++f)
      wv[f] = *(const f16x8*)(src + (size_t)f * 512);
  }
  for (int i = tid; i < 1664; i += 1024) svl[i] = Sv[i];
  for (int i = tid; i < 16 * HPAD; i += 1024) hbuf[i] = (f16)0.0f;

  const int gb = tid >> 6;          // gate-phase batch (== w)
  const int gc = tid & 63;          // gate-phase base channel
  float creg[6] = {};
  __syncthreads();

  for (int t = 0; t < 50; ++t) {
    // ---- P1: gate-xk prefetch + MFMA over h(t-1) ----
    const f16* xrow = XKh + ((size_t)(b0 + gb) * 50 + t) * GP;
    f16 xkg[4][6];
#pragma unroll
    for (int G = 0; G < 4; ++G)
#pragma unroll
      for (int j = 0; j < 6; ++j)
        xkg[G][j] = xrow[24 + G * 384 + gc + j * 64];
    const float tvb = timep[(b0 + gb) * 50 + t];

    f16x8 af[6];
#pragma unroll
    for (int i = 0; i < 6; ++i)
      af[i] = *(const f16x8*)(hbuf + r16 * HPAD + (kh * 6 + i) * 32 + q * 8);
    f32x4 acc[13];
#pragma unroll
    for (int j = 0; j < 13; ++j) acc[j] = (f32x4){0.f, 0.f, 0.f, 0.f};
#pragma unroll
    for (int j = 0; j < 13; ++j)
#pragma unroll
      for (int i = 0; i < 6; ++i)
        acc[j] = __builtin_amdgcn_mfma_f32_16x16x32_f16(af[i], wv[j * 6 + i], acc[j], 0, 0, 0);
    if (kh == 0) {
#pragma unroll
      for (int j = 0; j < 13; ++j) {
        const int col = cs * 208 + j * 16 + r16;
#pragma unroll
        for (int rr = 0; rr < 4; ++rr)
          xol[(q * 4 + rr) * XOLN + col] = acc[j][rr];
      }
    }
    __syncthreads();                 // BAR1: half0 sums committed
    if (kh == 1) {
#pragma unroll
      for (int j = 0; j < 13; ++j) {
        const int col = cs * 208 + j * 16 + r16;
#pragma unroll
        for (int rr = 0; rr < 4; ++rr)
          xol[(q * 4 + rr) * XOLN + col] += acc[j][rr];
      }
    }
    __syncthreads();                 // BAR2: xol complete
    // ---- P3: cumax softmax ----
    if (tid < 192) {
      const int b = tid / 12, l = tid - (tid / 12) * 12;
      const f16* xr2 = XKh + ((size_t)(b0 + b) * 50 + t) * GP;
      const float tv2 = timep[(b0 + b) * 50 + t];
      float e1[12], e2[12], mx1 = -1e30f, mx2 = -1e30f;
#pragma unroll
      for (int c = 0; c < 12; ++c) {
        e1[c] = xol[b * XOLN + c] + (float)xr2[c] + tv2 * svl[c];
        mx1 = fmaxf(mx1, e1[c]);
        e2[c] = xol[b * XOLN + 12 + c] + (float)xr2[12 + c] + tv2 * svl[12 + c];
        mx2 = fmaxf(mx2, e2[c]);
      }
      float s1 = 0.f, s2 = 0.f;
#pragma unroll
      for (int c = 0; c < 12; ++c) {
        e1[c] = __expf(e1[c] - mx1); s1 += e1[c];
        e2[c] = __expf(e2[c] - mx2); s2 += e2[c];
      }
      float cum1 = 0.f;
      for (int c = 0; c <= l; ++c) cum1 += e1[c];
      fml[b * 12 + l] = cum1 / s1;
      float cum2 = 0.f;
      for (int c = 11; c >= l; --c) cum2 += e2[c];
      iml[b * 12 + l] = cum2 / s2;
      if (l == 0) {
        float ds = 0.f;
#pragma unroll
        for (int c = 0; c < 12; ++c) ds += (float)(12 - c) * e1[c];
        dists[t * 256 + b0 + b] = 1.0f - ds / (12.0f * s1);
      }
    }
    __syncthreads();                 // BAR3: fm/im ready
    // ---- P4: gate math (all 1024 threads, 6 channels each) ----
#pragma unroll
    for (int j = 0; j < 6; ++j) {
      const int ch = gc + j * 64;
      const int l = ch >> 5;
      const float fv = sigm(xol[gb * XOLN + 24 + ch]        + (float)xkg[0][j] + tvb * svl[24 + ch]);
      const float iv = sigm(xol[gb * XOLN + 24 + 384 + ch]  + (float)xkg[1][j] + tvb * svl[24 + 384 + ch]);
      const float og = sigm(xol[gb * XOLN + 24 + 768 + ch]  + (float)xkg[2][j] + tvb * svl[24 + 768 + ch]);
      const float ci = tanhfast(xol[gb * XOLN + 24 + 1152 + ch] + (float)xkg[3][j] + tvb * svl[24 + 1152 + ch]);
      const float fmv = fml[gb * 12 + l];
      const float imv = iml[gb * 12 + l];
      const float ov = fmv * imv;
      const float cn = ov * (fv * creg[j] + iv * ci) + (fmv - ov) * creg[j] + (imv - ov) * ci;
      creg[j] = cn;
      const float hv = og * tanhfast(cn);
      hbuf[gb * HPAD + ch] = (f16)hv;
      hall[((size_t)t * 256 + b0 + gb) * 384 + ch] = (f16)hv;  // plain, coalesced
    }
    __syncthreads();                 // BAR4: hbuf ready for next step
  }
}

// ld[b,t,:] = softmax_j(cumsum_j dist[t-9+j])
__global__ __launch_bounds__(256) void k_ld(const float* __restrict__ dists,
                                            float* __restrict__ ld) {
  int i = blockIdx.x * 256 + threadIdx.x;
  if (i >= 12800) return;
  int b = i / 50, t = i - b * 50;
  float v[10];
  float cum = 0.0f, mx = -1e30f;
#pragma unroll
  for (int j = 0; j < 10; j++) {
    int s = t - 9 + j;
    float d = (s >= 0) ? dists[s * 256 + b] : 0.0f;
    cum += d; v[j] = cum; mx = fmaxf(mx, cum);
  }
  float sum = 0.0f;
#pragma unroll
  for (int j = 0; j < 10; j++) { v[j] = __expf(v[j] - mx); sum += v[j]; }
  float inv = 1.0f / sum;
#pragma unroll
  for (int j = 0; j < 10; j++) ld[i * 10 + j] = v[j] * inv;
}

// mlh_h[(b,t)][h] = mean_j ld*h
__global__ __launch_bounds__(256) void k_mlh(const float* __restrict__ ld,
                                             const f16* __restrict__ h_all,
                                             f16* __restrict__ mlh) {
  int i = blockIdx.x * 256 + threadIdx.x;   // 12800*384
  int row = i / 384, h = i - row * 384;
  int b = row / 50, t = row - b * 50;
  float acc = 0.0f;
#pragma unroll
  for (int j = 0; j < 10; j++) {
    int s = t - 9 + j;
    if (s >= 0) acc += ld[row * 10 + j] * (float)h_all[((size_t)s * 256 + b) * 384 + h];
  }
  mlh[i] = (f16)(acc * 0.1f);
}

// rnn_f16[b][t*384+h] = theme*(conv0+conv1+conv_b) + h
__global__ __launch_bounds__(256) void k_rnn(const float* __restrict__ theme,
                                             const float* __restrict__ convp,
                                             const float* __restrict__ cb,
                                             const f16* __restrict__ h_all,
                                             f16* __restrict__ rnn) {
  int i = blockIdx.x * 256 + threadIdx.x;   // 12800*384, ordered (b,t,h)
  int row = i / 384, h = i - row * 384;
  int b = row / 50, t = row - b * 50;
  float conv = convp[i] + convp[4915200 + i] + cb[h];
  float local = theme[i] * conv;
  float hv = (float)h_all[((size_t)t * 256 + b) * 384 + h];
  rnn[i] = (f16)(local + hv);
}

// out[i] = sum_z part[z][i] + out_b
__global__ __launch_bounds__(256) void k_red(const float* __restrict__ part,
                                             const float* __restrict__ ob,
                                             float* __restrict__ out) {
  int i = blockIdx.x * 256 + threadIdx.x;   // 32768
  float s = 0.0f;
#pragma unroll
  for (int z = 0; z < ZSPLIT; z++) s += part[z * 32768 + i];
  out[i] = s + ob[i & 127];
}

// ---------------- launch ----------------
extern "C" void kernel_launch(void* const* d_in, const int* in_sizes, int n_in,
                              void* d_out, int out_size, void* d_ws, size_t ws_size,
                              hipStream_t stream) {
  (void)in_sizes; (void)n_in; (void)out_size; (void)ws_size;
  const int*   node_ids  = (const int*)  d_in[0];
  const float* timep     = (const float*)d_in[3];
  const float* embed     = (const float*)d_in[6];
  const float* kernel_w  = (const float*)d_in[7];
  const float* kernel_b  = (const float*)d_in[8];
  const float* rec_w     = (const float*)d_in[9];
  const float* rec_b     = (const float*)d_in[10];
  const float* scale_w   = (const float*)d_in[11];
  const float* scale_b   = (const float*)d_in[12];
  const float* rescale_w = (const float*)d_in[13];
  const float* rescale_b = (const float*)d_in[14];
  const float* conv_w    = (const float*)d_in[15];
  const float* conv_b    = (const float*)d_in[16];
  const float* out_w     = (const float*)d_in[17];
  const float* out_b     = (const float*)d_in[18];

  char* ws = (char*)d_ws;
  float* opart   = (float*)(ws + OFF_OPART);
  f16*   Wk      = (f16*)  (ws + OFF_WK);
  f16*   XKh     = (f16*)  (ws + OFF_XK);
  f16*   mlh_h   = (f16*)  (ws + OFF_MLH);
  f16*   s1h     = (f16*)  (ws + OFF_S1);
  float* theme   = (float*)(ws + OFF_TH);
  float* convbuf = (float*)(ws + OFF_CV);
  f16*   swp     = (f16*)  (ws + OFF_SWP);
  f16*   rwp2    = (f16*)  (ws + OFF_RWP2);
  float* sbp     = (float*)(ws + OFF_SBP);
  f16*   RWn     = (f16*)  (ws + OFF_RW);
  float* Sv      = (float*)(ws + OFF_SV);
  int*   bar     = (int*)  (ws + OFF_BAR);
  float* biasc   = (float*)(ws + OFF_BIASC);
  f16*   h_all   = (f16*)  (ws + OFF_HALL);
  float* ldbuf   = (float*)(ws + OFF_LD);
  f16*   Wc2     = (f16*)  (ws + OFF_WC2);
  f16*   rnn     = (f16*)  (ws + OFF_RNN);
  f16*   outw    = (f16*)  (ws + OFF_OUTW);
  f16*   Eh      = (f16*)  (ws + OFF_EH);

  float* outp  = (float*)d_out;          // (256,128)
  float* dists = outp + 256 * 128;       // (50,256)

  // phase 0: prep
  k_prep_wk  <<<26624, 256, 0, stream>>>(kernel_w, kernel_b, rec_b, Wk, biasc);
  k_prep_misc<<<10457, 512, 0, stream>>>(rec_w, kernel_w, scale_w, scale_b, rescale_w,
                                         conv_w, out_w, embed,
                                         RWn, Sv, bar, swp, sbp, rwp2, Wc2, outw, Eh);
  // phase 1: XKh GEMM with fused embedding gather (BK=64 dual-subtile staging)
  k_gemm_emb<<<dim3(100, 13), 256, 0, stream>>>(node_ids, Eh, Wk, XKh, biasc);
  // phase 2: recurrence — 16 independent blocks, register-stationary weights,
  // no cooperative launch, no inter-block sync.
  {
    hipFuncSetAttribute((const void*)k_recur_fused,
                        hipFuncAttributeMaxDynamicSharedMemorySize, FUSED_LDS);
    k_recur_fused<<<16, 1024, FUSED_LDS, stream>>>(XKh, RWn, Sv, timep, h_all, dists);
  }
  // phase 3: deferred outputs (lh fused into conv GEMM staging)
  k_ld  <<<50,    256, 0, stream>>>(dists, ldbuf);
  k_mlh <<<19200, 256, 0, stream>>>(ldbuf, h_all, mlh_h);
  k_gemm_bt<<<dim3(100, 1), 256, 0, stream>>>(mlh_h, swp, s1h, sbp, 128, 384, 384, 2);
  k_gemm_bt<<<dim3(100, 3), 256, 0, stream>>>(s1h, rwp2, theme, rescale_b, 384, 128, 128, 3);
  k_gemm_conv<<<dim3(100, 3, 2), 256, 0, stream>>>(ldbuf, h_all, Wc2, convbuf);
  k_rnn <<<19200, 256, 0, stream>>>(theme, convbuf, conv_b, h_all, rnn);
  // phase 4: out = rnn @ out_w^T + out_b   (K split 40 ways: 480 = 15*32, exact)
  k_gemm_bt<<<dim3(2, 1, ZSPLIT), 256, 0, stream>>>(rnn, outw, opart, nullptr, 128, KO, KO / ZSPLIT, 0);
  k_red<<<128, 256, 0, stream>>>(opart, out_b, outp);
}

// Round 8
// 933.914 us; speedup vs baseline: 2.8976x; 2.8976x over previous
//
#include <hip/hip_runtime.h>
#include <math.h>

// ---------------- types ----------------
typedef _Float16 f16;
typedef _Float16 f16x8 __attribute__((ext_vector_type(8)));
typedef float f32x4 __attribute__((ext_vector_type(4)));
typedef unsigned int u32;
typedef u32 u32x4 __attribute__((ext_vector_type(4)));

#define DEV static __device__ __forceinline__

DEV float sigm(float x)  { return 1.0f / (1.0f + __expf(-x)); }
DEV float tanhfast(float x) { return 2.0f / (1.0f + __expf(-2.0f * x)) - 1.0f; }

// async global->LDS, 16B per lane (dest must be wave-uniform base + lane*16)
DEV void gld16(const void* g, void* l) {
  __builtin_amdgcn_global_load_lds((const __attribute__((address_space(1))) void*)g,
                                   (__attribute__((address_space(3))) void*)l, 16, 0, 0);
}

// init-only barrier (release/acquire) — used once before the t-loop
DEV void gbar(int* bar, int nblk) {
  __syncthreads();
  if (threadIdx.x == 0) {
    int* cnt = bar;
    int* gen = bar + 16;
    int g = __hip_atomic_load(gen, __ATOMIC_RELAXED, __HIP_MEMORY_SCOPE_AGENT);
    int a = __hip_atomic_fetch_add(cnt, 1, __ATOMIC_RELEASE, __HIP_MEMORY_SCOPE_AGENT);
    if (a == nblk - 1) {
      __hip_atomic_store(cnt, 0, __ATOMIC_RELAXED, __HIP_MEMORY_SCOPE_AGENT);
      __hip_atomic_store(gen, g + 1, __ATOMIC_RELEASE, __HIP_MEMORY_SCOPE_AGENT);
    } else {
      while (__hip_atomic_load(gen, __ATOMIC_RELAXED, __HIP_MEMORY_SCOPE_AGENT) == g)
        __builtin_amdgcn_s_sleep(1);
    }
    (void)__hip_atomic_load(gen, __ATOMIC_ACQUIRE, __HIP_MEMORY_SCOPE_AGENT);
  }
  __syncthreads();
}

// ---------------- problem constants ----------------
// B=256 V=50 N=32 D=128 H=384 L=12 CS=10 ND=4096 G=1560 OUT=128
#define GP 1664   // padded G (13*128) — XK gemm N and XKh row stride
#define KH 3840   // H*CS (conv gemm K)
#define KO 19200  // V*H  (out gemm K)
#define ZSPLIT 40 // out gemm K-split (19200/40 = 480 = 15*32, exact)
#define NGRP 16
#define NMEM 12
#define NBLK 192
#define XOLS 164  // xo local (LDS) row stride in f32
// Wl 10 tiles + xol 16x164 f32 + hl staging 512 f16
#define RECUR_LDS (122880 + 10496 + 1024)

// ---------------- workspace layout (bytes) ----------------
static constexpr size_t OFF_OPART = 0;                       // out partials 40*32768*4 = 5.24MB
static constexpr size_t OFF_ZB    = 104857600 - 262144;      // zbuf f16 196608
static constexpr size_t OFF_WK    = 104857600;               // 13631488
static constexpr size_t OFF_XK    = OFF_WK + 13631488;       // XKh f16 42598400
// aliases of the XK region (XKh dead after k_recur):
static constexpr size_t OFF_MLH   = OFF_XK;                  // mlh_h f16 9830400
static constexpr size_t OFF_S1    = OFF_XK + 9830400;        // s1h f16 3276800
static constexpr size_t OFF_TH    = OFF_XK + 13107200;       // theme f32 19660800
static constexpr size_t OFF_CV    = OFF_XK + 32768000;       // conv partials 2x19660800 (ends +72089600)
static constexpr size_t OFF_SWP   = OFF_XK + 72089600;       // swp f16 98304 (> XKh end)
static constexpr size_t OFF_RWP2  = OFF_XK + 72187904;       // rwp2 f16 98304
static constexpr size_t OFF_SBP   = OFF_XK + 72286208;       // sbp f32 512
static constexpr size_t OFF_RW    = OFF_XK + 85196800;       // RWpack f16 1474560
static constexpr size_t OFF_SV    = OFF_RW + 1474560;        // Sv f32 6656 (pad 8192)
static constexpr size_t OFF_BAR   = OFF_SV + 8192;           // flags + init bar (32 KB)
static constexpr size_t OFF_BIASC = OFF_BAR + 32768;         // 8192
static constexpr size_t OFF_HALL  = OFF_BIASC + 8192;        // h_all f16 9830400
static constexpr size_t OFF_LD    = OFF_HALL + 9830400;      // 512000
static constexpr size_t OFF_WC2   = OFF_LD + 512000;         // 2949120
static constexpr size_t OFF_RNN   = OFF_WC2 + 2949120;       // 9830400
static constexpr size_t OFF_OUTW  = OFF_RNN + 9830400;       // 4915200
static constexpr size_t OFF_EH    = OFF_OUTW + 4915200;      // embed f16 2560256

// ---------------- kernels ----------------

// kernel_w (1560 x 4097) -> Wk_f16 (1664 x 4096, zero-padded rows); biasc = kb+rb (padded 1664)
__global__ __launch_bounds__(256) void k_prep_wk(const float* __restrict__ kw,
                                                 const float* __restrict__ kb,
                                                 const float* __restrict__ rb,
                                                 f16* __restrict__ Wk,
                                                 float* __restrict__ biasc) {
  long i = (long)blockIdx.x * 256 + threadIdx.x;
  if (i < 1664L * 4096) {
    int nn = (int)(i >> 12);
    int k  = (int)(i & 4095);
    float v = (nn < 1560) ? kw[(long)nn * 4097 + k] : 0.0f;
    Wk[i] = (f16)v;
  }
  if (i < 1664) biasc[i] = (i < 1560) ? (kb[i] + rb[i]) : 0.0f;
}

// merged small prep: [0,180) rwpack+Sv+bar, [180,276) scale pack, [276,3156) conv_w pack,
// [3156,7956) out_w cvt, [7956,10457) embed cvt
__global__ __launch_bounds__(512) void k_prep_misc(const float* __restrict__ rw,
                                                   const float* __restrict__ kw,
                                                   const float* __restrict__ sw,
                                                   const float* __restrict__ sb,
                                                   const float* __restrict__ rw2,
                                                   const float* __restrict__ cw,
                                                   const float* __restrict__ ow,
                                                   const float* __restrict__ embed,
                                                   f16* __restrict__ RWp,
                                                   float* __restrict__ Sv,
                                                   int* __restrict__ bar,
                                                   f16* __restrict__ swp,
                                                   float* __restrict__ sbp,
                                                   f16* __restrict__ rwp2,
                                                   f16* __restrict__ Wc2,
                                                   f16* __restrict__ outw,
                                                   f16* __restrict__ Eh) {
  const int blk = blockIdx.x, tid = threadIdx.x;
  if (blk < 180) {
    int i = blk * 512 + tid;                 // 92160 chunks of 8 halfs
    if (i < 92160) {
      int p = i / 7680;
      int rem = i - p * 7680;
      int tau = rem / 768;
      int r2 = rem - tau * 768;
      int f = r2 >> 6;
      int l = r2 & 63;
      int lc = tau * 16 + (l & 15);
      int n;
      if (lc < 24) n = lc;
      else if (lc < 32) n = -1;
      else { int run = (lc - 32) >> 5; n = 24 + (run * 12 + p) * 32 + ((lc - 32) & 31); }
      int k = f * 32 + ((l >> 4) << 3);
      f16x8 o;
      if (n >= 0) {
        const float* s = rw + (long)n * 385 + k;
#pragma unroll
        for (int e = 0; e < 8; ++e) o[e] = (f16)s[e];
      } else {
#pragma unroll
        for (int e = 0; e < 8; ++e) o[e] = (f16)0.0f;
      }
      *(f16x8*)(RWp + (long)i * 8) = o;
    }
    if (i < 1664)
      Sv[i] = (i < 1560) ? (rw[(long)i * 385 + 384] + kw[(long)i * 4097 + 4096]) : 0.0f;
    if (i < 8192) bar[i] = 0;
  } else if (blk < 276) {
    int i = (blk - 180) * 512 + tid;         // 49152
    if (i < 128 * 384) {
      int o = i / 384, k = i - o * 384;
      swp[i] = (f16)((o < 64) ? sw[o * 384 + k] : 0.0f);
      int o2 = i >> 7, k2 = i & 127;
      rwp2[i] = (f16)((k2 < 64) ? rw2[o2 * 64 + k2] : 0.0f);
    }
    if (i < 128) sbp[i] = (i < 64) ? sb[i] : 0.0f;
  } else if (blk < 3156) {
    int i = (blk - 276) * 512 + tid;         // 384*3840 = 1474560
    if (i < 384 * 3840) {
      int o = i / 3840;
      int c = i - o * 3840;
      int j = c / 384;
      int h = c - j * 384;
      Wc2[i] = (f16)cw[((long)o * 384 + h) * 10 + j];
    }
  } else if (blk < 7956) {
    long i = (long)(blk - 3156) * 512 + tid; // 2457600
    if (i < 128L * KO) outw[i] = (f16)ow[i];
  } else {
    long i = (long)(blk - 7956) * 512 + tid; // 1280128
    if (i < 10001L * 128) Eh[i] = (f16)embed[i];
  }
}

// XKh = f16( gather(embed_h, ids) @ Wk^T + biasc ).
// v5: 256x128 tile (was 128x128) — halves B-streaming traffic (each row-block
// streams the full 13.6MB Wk; 50 row-blocks instead of 100) and halves the
// barrier-drain count per output. 4 waves, per-wave acc[4][8] (128 VGPR);
// __launch_bounds__(256,2) caps at 256 VGPR/wave (budget ~210, no spill).
// Dual 32-K subtile staging (BK=64) and register id-prefetch retained.
__global__ __launch_bounds__(256, 2) void k_gemm_emb(const int* __restrict__ ids,  // (12800,32)
                                                     const f16* __restrict__ Eh,  // (10001,128)
                                                     const f16* __restrict__ W,   // (1664,4096)
                                                     f16* __restrict__ C,         // (12800,GP)
                                                     const float* __restrict__ bias) {
  __shared__ __align__(16) f16 As0[256 * 32];
  __shared__ __align__(16) f16 As1[256 * 32];
  __shared__ __align__(16) f16 Bs0[128 * 32];
  __shared__ __align__(16) f16 Bs1[128 * 32];
  const int tid = threadIdx.x;
  // nwg = 50*13 = 650; q = 81, r = 2 — bijective XCD chunk map (m204)
  const int W0  = blockIdx.y * 50 + blockIdx.x;
  const int xcd = W0 & 7, idx = W0 >> 3;
  const int nw  = (xcd < 2) ? (xcd * 82 + idx) : (164 + (xcd - 2) * 81 + idx);
  const int bx  = nw % 50, by = nw / 50;
  const long rowA0 = (long)bx * 256;
  const long rowB0 = (long)by * 128;
  const int w = tid >> 6, lane = tid & 63;
  const int q = lane >> 4, r16 = lane & 15;
  f32x4 acc[4][8] = {};
  const int srow = tid >> 2;
  const int scol = (tid & 3) * 8;
  const int* idr0 = ids + (rowA0 + srow) * 32;
  const int* idr1 = idr0 + 64 * 32;
  const int* idr2 = idr0 + 128 * 32;
  const int* idr3 = idr0 + 192 * 32;
  const f16* gB0 = W + (rowB0 + srow) * 4096L + scol;
  const f16* gB1 = gB0 + 64L * 4096;
  f16* lA0 = As0 + tid * 8;
  f16* lA1 = As1 + tid * 8;
  f16* lB0 = Bs0 + tid * 8;
  f16* lB1 = Bs1 + tid * 8;
  int cur0 = idr0[0], cur1 = idr1[0], cur2 = idr2[0], cur3 = idr3[0];
  for (int n = 0; n < 32; ++n) {
    // prefetch next group's ids — 2 barrier-pairs of slack before use
    int nx0 = 0, nx1 = 0, nx2 = 0, nx3 = 0;
    if (n < 31) { nx0 = idr0[n + 1]; nx1 = idr1[n + 1]; nx2 = idr2[n + 1]; nx3 = idr3[n + 1]; }
#pragma unroll
    for (int kk = 0; kk < 2; ++kk) {
      const int k0 = n * 128 + kk * 64;
      const int d = kk * 64 + scol;
      __syncthreads();
      gld16(Eh + (size_t)cur0 * 128 + d,      lA0);
      gld16(Eh + (size_t)cur1 * 128 + d,      lA0 + 2048);
      gld16(Eh + (size_t)cur2 * 128 + d,      lA0 + 4096);
      gld16(Eh + (size_t)cur3 * 128 + d,      lA0 + 6144);
      gld16(Eh + (size_t)cur0 * 128 + d + 32, lA1);
      gld16(Eh + (size_t)cur1 * 128 + d + 32, lA1 + 2048);
      gld16(Eh + (size_t)cur2 * 128 + d + 32, lA1 + 4096);
      gld16(Eh + (size_t)cur3 * 128 + d + 32, lA1 + 6144);
      gld16(gB0 + k0,      lB0);
      gld16(gB1 + k0,      lB0 + 2048);
      gld16(gB0 + k0 + 32, lB1);
      gld16(gB1 + k0 + 32, lB1 + 2048);
      __syncthreads();
      f16x8 af[4], bf[8];
#pragma unroll
      for (int i = 0; i < 4; i++)
        af[i] = *(const f16x8*)&As0[(w * 64 + i * 16 + r16) * 32 + q * 8];
#pragma unroll
      for (int j = 0; j < 8; j++)
        bf[j] = *(const f16x8*)&Bs0[(j * 16 + r16) * 32 + q * 8];
#pragma unroll
      for (int i = 0; i < 4; i++)
#pragma unroll
        for (int j = 0; j < 8; j++)
          acc[i][j] = __builtin_amdgcn_mfma_f32_16x16x32_f16(af[i], bf[j], acc[i][j], 0, 0, 0);
#pragma unroll
      for (int i = 0; i < 4; i++)
        af[i] = *(const f16x8*)&As1[(w * 64 + i * 16 + r16) * 32 + q * 8];
#pragma unroll
      for (int j = 0; j < 8; j++)
        bf[j] = *(const f16x8*)&Bs1[(j * 16 + r16) * 32 + q * 8];
#pragma unroll
      for (int i = 0; i < 4; i++)
#pragma unroll
        for (int j = 0; j < 8; j++)
          acc[i][j] = __builtin_amdgcn_mfma_f32_16x16x32_f16(af[i], bf[j], acc[i][j], 0, 0, 0);
    }
    cur0 = nx0; cur1 = nx1; cur2 = nx2; cur3 = nx3;
  }
#pragma unroll
  for (int i = 0; i < 4; i++)
#pragma unroll
    for (int j = 0; j < 8; j++) {
      long row = rowA0 + w * 64 + i * 16 + q * 4;
      long col = rowB0 + j * 16 + r16;
      float bv = bias[col];
#pragma unroll
      for (int r = 0; r < 4; r++)
        C[(row + r) * (long)GP + col] = (f16)(acc[i][j][r] + bv);
    }
}

// conv GEMM with lh fused into A-staging
__global__ __launch_bounds__(256) void k_gemm_conv(const float* __restrict__ ld,   // (12800,10)
                                                   const f16* __restrict__ h_all, // (50,256,384)
                                                   const f16* __restrict__ W,     // Wc2 (384,3840)
                                                   float* __restrict__ C) {
  __shared__ __align__(16) f16 As[128 * 32];
  __shared__ __align__(16) f16 Bs[128 * 32];
  const int tid = threadIdx.x;
  const long rowA0 = (long)blockIdx.x * 128;
  const long rowB0 = (long)blockIdx.y * 128;
  const int ks = blockIdx.z * 1920;
  const long zoff = (long)blockIdx.z * (12800L * 384);
  const int w = tid >> 6, lane = tid & 63;
  const int q = lane >> 4, r16 = lane & 15;
  const int wr = w >> 1, wc = w & 1;
  f32x4 acc[4][4] = {};
  const int srow = tid >> 2;
  const int scol = (tid & 3) * 8;
  const int row0 = (int)rowA0 + srow, row1 = row0 + 64;
  const int b0r = row0 / 50, t0r = row0 - b0r * 50;
  const int b1r = row1 / 50, t1r = row1 - b1r * 50;
  const f16* gB0 = W + (rowB0 + srow) * (long)KH + ks + scol;
  const f16* gB1 = gB0 + 64L * KH;
  f16* lB = Bs + tid * 8;
  for (int k0 = 0; k0 < 1920; k0 += 32) {
    const int col0 = ks + k0;
    const int j = col0 / 384;
    const int hh = col0 - j * 384 + scol;
    const int s0 = t0r - 9 + j, s1 = t1r - 9 + j;
    __syncthreads();
    gld16(gB0 + k0, lB);
    gld16(gB1 + k0, lB + 2048);
    f16x8 a0v = {}, a1v = {};
    if (s0 >= 0) {
      const float lv = ld[row0 * 10 + j];
      f16x8 hv = *(const f16x8*)(h_all + ((size_t)s0 * 256 + b0r) * 384 + hh);
#pragma unroll
      for (int e = 0; e < 8; ++e) a0v[e] = (f16)((float)hv[e] * lv);
    }
    if (s1 >= 0) {
      const float lv = ld[row1 * 10 + j];
      f16x8 hv = *(const f16x8*)(h_all + ((size_t)s1 * 256 + b1r) * 384 + hh);
#pragma unroll
      for (int e = 0; e < 8; ++e) a1v[e] = (f16)((float)hv[e] * lv);
    }
    *(f16x8*)&As[srow * 32 + scol] = a0v;
    *(f16x8*)&As[(srow + 64) * 32 + scol] = a1v;
    __syncthreads();
    f16x8 af[4], bfr[4];
#pragma unroll
    for (int i = 0; i < 4; i++) {
      af[i]  = *(const f16x8*)&As[(wr * 64 + i * 16 + r16) * 32 + q * 8];
      bfr[i] = *(const f16x8*)&Bs[(wc * 64 + i * 16 + r16) * 32 + q * 8];
    }
#pragma unroll
    for (int i = 0; i < 4; i++)
#pragma unroll
      for (int j2 = 0; j2 < 4; j2++)
        acc[i][j2] = __builtin_amdgcn_mfma_f32_16x16x32_f16(af[i], bfr[j2], acc[i][j2], 0, 0, 0);
  }
#pragma unroll
  for (int i = 0; i < 4; i++)
#pragma unroll
    for (int j2 = 0; j2 < 4; j2++) {
      long row = rowA0 + wr * 64 + i * 16 + q * 4;
      long col = rowB0 + wc * 64 + j2 * 16 + r16;
#pragma unroll
      for (int r = 0; r < 4; r++)
        C[(row + r) * 384L + col + zoff] = acc[i][j2][r];
    }
}

// C = A(M x K) * W(N x K)^T (+bias[col]); m97-style global_load_lds staging.
__global__ __launch_bounds__(256) void k_gemm_bt(const f16* __restrict__ A,
                                                 const f16* __restrict__ W,
                                                 void* __restrict__ Cv,
                                                 const float* __restrict__ bias,
                                                 int N, int K, int kLen, int act) {
  __shared__ __align__(16) f16 As[128 * 32];
  __shared__ __align__(16) f16 Bs[128 * 32];
  const int tid = threadIdx.x;
  const long rowA0 = (long)blockIdx.x * 128;
  const long rowB0 = (long)blockIdx.y * 128;
  const long ks = (long)blockIdx.z * kLen;
  const long zoff = (long)blockIdx.z * ((long)gridDim.x * 128 * N);
  const int w = tid >> 6, lane = tid & 63;
  const int q = lane >> 4, r16 = lane & 15;
  const int wr = w >> 1, wc = w & 1;
  f32x4 acc[4][4] = {};
  const int srow = tid >> 2;
  const int scol = (tid & 3) * 8;
  const f16* gA0 = A + (rowA0 + srow) * (long)K + ks + scol;
  const f16* gA1 = gA0 + 64L * K;
  const f16* gB0 = W + (rowB0 + srow) * (long)K + ks + scol;
  const f16* gB1 = gB0 + 64L * K;
  f16* lA = As + tid * 8;
  f16* lB = Bs + tid * 8;
  for (int k0 = 0; k0 < kLen; k0 += 32) {
    __syncthreads();
    gld16(gA0 + k0, lA);
    gld16(gA1 + k0, lA + 2048);
    gld16(gB0 + k0, lB);
    gld16(gB1 + k0, lB + 2048);
    __syncthreads();
    f16x8 af[4], bfr[4];
#pragma unroll
    for (int i = 0; i < 4; i++) {
      af[i]  = *(const f16x8*)&As[(wr * 64 + i * 16 + r16) * 32 + q * 8];
      bfr[i] = *(const f16x8*)&Bs[(wc * 64 + i * 16 + r16) * 32 + q * 8];
    }
#pragma unroll
    for (int i = 0; i < 4; i++)
#pragma unroll
      for (int j = 0; j < 4; j++)
        acc[i][j] = __builtin_amdgcn_mfma_f32_16x16x32_f16(af[i], bfr[j], acc[i][j], 0, 0, 0);
  }
#pragma unroll
  for (int i = 0; i < 4; i++)
#pragma unroll
    for (int j = 0; j < 4; j++) {
      long row = rowA0 + wr * 64 + i * 16 + q * 4;
      long col = rowB0 + wc * 64 + j * 16 + r16;
      float bv = bias ? bias[col] : 0.0f;
#pragma unroll
      for (int r = 0; r < 4; r++) {
        float v = acc[i][j][r] + bv;
        long off = (row + r) * (long)N + col + zoff;
        if (act == 0)      ((float*)Cv)[off] = v;
        else if (act == 1) ((f16*)Cv)[off]   = (f16)v;
        else if (act == 2) ((f16*)Cv)[off]   = (f16)fmaxf(v, 0.0f);
        else               ((float*)Cv)[off] = sigm(v);
      }
    }
}

// gate-partitioned weights-stationary recurrence v4 (R1/R4/R6-proven, 353 µs):
// 192 blocks = 16 groups x 12 members, 640 threads. h-exchange staged through
// LDS, wave 0 emits ONE coalesced global_store_dwordx4 sc0 sc1 (LLC-direct),
// drains (per-wave vmcnt => correct release), then raw flag store. Wave 1
// polls flags (overlaps wave 0's drain). LESSONS: (R5) do NOT distribute the
// poll across waves — agent-scope spin loops in 10 waves flooded the LLC
// (WRITE_SIZE 10MB->1.1GB). (R7) rec_w (1.28MB) can NOT be register-stationary
// on one CU — CU VGPR file = 2048 wave-regs total; the 12-member LDS split is
// the right partition.
__global__ __launch_bounds__(640)
void k_recur_coop(const f16* __restrict__ XKh,
                  const f16* __restrict__ RWp,
                  const float* __restrict__ Sv,
                  const float* __restrict__ timep,
                  f16* __restrict__ zbuf,
                  f16* __restrict__ hall,
                  float* __restrict__ dists,
                  int* __restrict__ bar) {
  extern __shared__ char smem[];
  f16*   Wl  = (f16*)smem;
  float* xol = (float*)(smem + 122880);
  f16*   hl  = (f16*)(smem + 122880 + 10496);   // 512 f16 h-staging
  const int tid = threadIdx.x;
  const int g = blockIdx.x / NMEM;
  const int m = blockIdx.x - g * NMEM;
  const int b0 = g * 16;
  int* gflags = bar + g * 256;
  int* ibar   = bar + 4096 + g * 32;
  const int w = tid >> 6, lane = tid & 63;
  const int q = lane >> 4, r16 = lane & 15;
  {
    const f16* src = RWp + (size_t)m * 61440;
    for (int i = tid; i < 7680; i += 640)
      *(f16x8*)(Wl + (size_t)i * 8) = *(const f16x8*)(src + (size_t)i * 8);
  }
  int ncol = -1; float Svc = 0.0f;
  if (w < 10) {
    const int lc = w * 16 + r16;
    if (lc < 24) ncol = lc;
    else if (lc >= 32) { int run = (lc - 32) >> 5; ncol = 24 + (run * 12 + m) * 32 + ((lc - 32) & 31); }
    if (ncol >= 0) Svc = Sv[ncol];
  }
  {
    f16x8 z = {};
    for (int i = m * 640 + tid; i < 768; i += NMEM * 640)
      *(f16x8*)(zbuf + (size_t)b0 * 384 + (size_t)i * 8) = z;
  }
  gbar(ibar, NMEM);

  const int ch = tid & 31, bloc = tid >> 5;
  float creg = 0.0f;
  f16 xkc[4] = {};
  if (w < 10 && ncol >= 0) {
#pragma unroll
    for (int r = 0; r < 4; ++r)
      xkc[r] = XKh[((long)(b0 + q * 4 + r) * 50) * GP + ncol];
  }

  for (int t = 0; t < 50; ++t) {
    const f16* hprev = (t == 0) ? zbuf : (hall + (size_t)(t - 1) * 98304);
    f16 xkn[4] = {};
    if (w < 10) {
      f16x8 af[12];
      const f16* ab = hprev + (size_t)(b0 + r16) * 384 + q * 8;
#pragma unroll
      for (int f = 0; f < 12; ++f) af[f] = *(const f16x8*)(ab + f * 32);
      if (t < 49 && ncol >= 0) {
#pragma unroll
        for (int r = 0; r < 4; ++r)
          xkn[r] = XKh[((long)(b0 + q * 4 + r) * 50 + (t + 1)) * GP + ncol];
      }
      float tv4[4];
#pragma unroll
      for (int r = 0; r < 4; ++r) tv4[r] = timep[(b0 + q * 4 + r) * 50 + t];
      const f16* bp = Wl + (size_t)w * 6144 + lane * 8;
      f32x4 a0 = {};
#pragma unroll
      for (int f = 0; f < 12; ++f)
        a0 = __builtin_amdgcn_mfma_f32_16x16x32_f16(af[f], *(const f16x8*)(bp + f * 512), a0, 0, 0, 0);
      const int lc = w * 16 + r16;
#pragma unroll
      for (int r = 0; r < 4; ++r)
        xol[(q * 4 + r) * XOLS + lc] = a0[r] + (float)xkc[r] + tv4[r] * Svc;
    }
    __syncthreads();
    if (bloc < 16) {
      const int gb = b0 + bloc;
      const float* xr = xol + bloc * XOLS;
      float e1[12], e2[12], mx1 = -1e30f, mx2 = -1e30f;
#pragma unroll
      for (int l = 0; l < 12; ++l) {
        e1[l] = xr[l];      mx1 = fmaxf(mx1, e1[l]);
        e2[l] = xr[12 + l]; mx2 = fmaxf(mx2, e2[l]);
      }
      float s1 = 0.0f, s2 = 0.0f;
#pragma unroll
      for (int l = 0; l < 12; ++l) {
        e1[l] = __expf(e1[l] - mx1); s1 += e1[l];
        e2[l] = __expf(e2[l] - mx2); s2 += e2[l];
      }
      float cum1 = 0.0f;
      for (int l = 0; l <= m; ++l) cum1 += e1[l];
      const float fmv = cum1 / s1;
      float cum2 = 0.0f;
      for (int l = 11; l >= m; --l) cum2 += e2[l];
      const float imv = cum2 / s2;
      if (m == 0 && ch == 0) {
        float ds = 0.0f;
#pragma unroll
        for (int l = 0; l < 12; ++l) ds += (float)(12 - l) * e1[l];
        dists[t * 256 + gb] = 1.0f - ds / (12.0f * s1);
      }
      const float fv = sigm(xr[32 + ch]);
      const float iv = sigm(xr[64 + ch]);
      const float og = sigm(xr[96 + ch]);
      const float ci = tanhfast(xr[128 + ch]);
      const float ov = fmv * imv;
      const float cn = ov * (fv * creg + iv * ci) + (fmv - ov) * creg + (imv - ov) * ci;
      creg = cn;
      const float hv = og * tanhfast(cn);
      hl[tid] = (f16)hv;    // stage to LDS; wave 0 emits one coalesced LLC store
    }
    __syncthreads();
    if (w == 0) {
      // lane l: row (l>>2) of the 16-batch slice, 16B chunk (l&3) of 64B —
      // one wave64 dwordx4 store covers the full 1 KB member h-slice.
      f32x4 d = *(const f32x4*)(hl + lane * 8);
      f16* dst = hall + ((size_t)t * 256 + b0 + (lane >> 2)) * 384 + m * 32 + (lane & 3) * 8;
      asm volatile("global_store_dwordx4 %0, %1, off sc0 sc1\n\t"
                   "s_waitcnt vmcnt(0)"
                   :: "v"(dst), "v"(d) : "memory");
      if (lane == 0) {
        int* fp = gflags + m * 16;
        int fv2 = t + 1;
        asm volatile("global_store_dword %0, %1, off sc0 sc1"
                     :: "v"(fp), "v"(fv2) : "memory");
      }
    }
    if (w == 1 && lane < NMEM) {
      while (__hip_atomic_load(gflags + lane * 16, __ATOMIC_RELAXED, __HIP_MEMORY_SCOPE_AGENT) < t + 1)
        __builtin_amdgcn_s_sleep(1);
    }
    __syncthreads();
    asm volatile("" ::: "memory");
#pragma unroll
    for (int r = 0; r < 4; ++r) xkc[r] = xkn[r];
  }
}

// ld[b,t,:] = softmax_j(cumsum_j dist[t-9+j])
__global__ __launch_bounds__(256) void k_ld(const float* __restrict__ dists,
                                            float* __restrict__ ld) {
  int i = blockIdx.x * 256 + threadIdx.x;
  if (i >= 12800) return;
  int b = i / 50, t = i - b * 50;
  float v[10];
  float cum = 0.0f, mx = -1e30f;
#pragma unroll
  for (int j = 0; j < 10; j++) {
    int s = t - 9 + j;
    float d = (s >= 0) ? dists[s * 256 + b] : 0.0f;
    cum += d; v[j] = cum; mx = fmaxf(mx, cum);
  }
  float sum = 0.0f;
#pragma unroll
  for (int j = 0; j < 10; j++) { v[j] = __expf(v[j] - mx); sum += v[j]; }
  float inv = 1.0f / sum;
#pragma unroll
  for (int j = 0; j < 10; j++) ld[i * 10 + j] = v[j] * inv;
}

// mlh_h[(b,t)][h] = mean_j ld*h
__global__ __launch_bounds__(256) void k_mlh(const float* __restrict__ ld,
                                             const f16* __restrict__ h_all,
                                             f16* __restrict__ mlh) {
  int i = blockIdx.x * 256 + threadIdx.x;   // 12800*384
  int row = i / 384, h = i - row * 384;
  int b = row / 50, t = row - b * 50;
  float acc = 0.0f;
#pragma unroll
  for (int j = 0; j < 10; j++) {
    int s = t - 9 + j;
    if (s >= 0) acc += ld[row * 10 + j] * (float)h_all[((size_t)s * 256 + b) * 384 + h];
  }
  mlh[i] = (f16)(acc * 0.1f);
}

// rnn_f16[b][t*384+h] = theme*(conv0+conv1+conv_b) + h
__global__ __launch_bounds__(256) void k_rnn(const float* __restrict__ theme,
                                             const float* __restrict__ convp,
                                             const float* __restrict__ cb,
                                             const f16* __restrict__ h_all,
                                             f16* __restrict__ rnn) {
  int i = blockIdx.x * 256 + threadIdx.x;   // 12800*384, ordered (b,t,h)
  int row = i / 384, h = i - row * 384;
  int b = row / 50, t = row - b * 50;
  float conv = convp[i] + convp[4915200 + i] + cb[h];
  float local = theme[i] * conv;
  float hv = (float)h_all[((size_t)t * 256 + b) * 384 + h];
  rnn[i] = (f16)(local + hv);
}

// out[i] = sum_z part[z][i] + out_b
__global__ __launch_bounds__(256) void k_red(const float* __restrict__ part,
                                             const float* __restrict__ ob,
                                             float* __restrict__ out) {
  int i = blockIdx.x * 256 + threadIdx.x;   // 32768
  float s = 0.0f;
#pragma unroll
  for (int z = 0; z < ZSPLIT; z++) s += part[z * 32768 + i];
  out[i] = s + ob[i & 127];
}

// ---------------- launch ----------------
extern "C" void kernel_launch(void* const* d_in, const int* in_sizes, int n_in,
                              void* d_out, int out_size, void* d_ws, size_t ws_size,
                              hipStream_t stream) {
  (void)in_sizes; (void)n_in; (void)out_size; (void)ws_size;
  const int*   node_ids  = (const int*)  d_in[0];
  const float* timep     = (const float*)d_in[3];
  const float* embed     = (const float*)d_in[6];
  const float* kernel_w  = (const float*)d_in[7];
  const float* kernel_b  = (const float*)d_in[8];
  const float* rec_w     = (const float*)d_in[9];
  const float* rec_b     = (const float*)d_in[10];
  const float* scale_w   = (const float*)d_in[11];
  const float* scale_b   = (const float*)d_in[12];
  const float* rescale_w = (const float*)d_in[13];
  const float* rescale_b = (const float*)d_in[14];
  const float* conv_w    = (const float*)d_in[15];
  const float* conv_b    = (const float*)d_in[16];
  const float* out_w     = (const float*)d_in[17];
  const float* out_b     = (const float*)d_in[18];

  char* ws = (char*)d_ws;
  float* opart   = (float*)(ws + OFF_OPART);
  f16*   zbuf    = (f16*)  (ws + OFF_ZB);
  f16*   Wk      = (f16*)  (ws + OFF_WK);
  f16*   XKh     = (f16*)  (ws + OFF_XK);
  f16*   mlh_h   = (f16*)  (ws + OFF_MLH);
  f16*   s1h     = (f16*)  (ws + OFF_S1);
  float* theme   = (float*)(ws + OFF_TH);
  float* convbuf = (float*)(ws + OFF_CV);
  f16*   swp     = (f16*)  (ws + OFF_SWP);
  f16*   rwp2    = (f16*)  (ws + OFF_RWP2);
  float* sbp     = (float*)(ws + OFF_SBP);
  f16*   RWp     = (f16*)  (ws + OFF_RW);
  float* Sv      = (float*)(ws + OFF_SV);
  int*   bar     = (int*)  (ws + OFF_BAR);
  float* biasc   = (float*)(ws + OFF_BIASC);
  f16*   h_all   = (f16*)  (ws + OFF_HALL);
  float* ldbuf   = (float*)(ws + OFF_LD);
  f16*   Wc2     = (f16*)  (ws + OFF_WC2);
  f16*   rnn     = (f16*)  (ws + OFF_RNN);
  f16*   outw    = (f16*)  (ws + OFF_OUTW);
  f16*   Eh      = (f16*)  (ws + OFF_EH);

  float* outp  = (float*)d_out;          // (256,128)
  float* dists = outp + 256 * 128;       // (50,256)

  // phase 0: prep
  k_prep_wk  <<<26624, 256, 0, stream>>>(kernel_w, kernel_b, rec_b, Wk, biasc);
  k_prep_misc<<<10457, 512, 0, stream>>>(rec_w, kernel_w, scale_w, scale_b, rescale_w,
                                         conv_w, out_w, embed,
                                         RWp, Sv, bar, swp, sbp, rwp2, Wc2, outw, Eh);
  // phase 1: XKh GEMM with fused embedding gather (256x128 tile, BK=64)
  k_gemm_emb<<<dim3(50, 13), 256, 0, stream>>>(node_ids, Eh, Wk, XKh, biasc);
  // phase 2: recurrence
  {
    hipFuncSetAttribute((const void*)k_recur_coop,
                        hipFuncAttributeMaxDynamicSharedMemorySize, RECUR_LDS);
    void* cargs[] = {(void*)&XKh, (void*)&RWp, (void*)&Sv, (void*)&timep,
                     (void*)&zbuf, (void*)&h_all, (void*)&dists, (void*)&bar};
    hipLaunchCooperativeKernel((void*)k_recur_coop, dim3(NBLK), dim3(640),
                               cargs, RECUR_LDS, stream);
  }
  // phase 3: deferred outputs (lh fused into conv GEMM staging)
  k_ld  <<<50,    256, 0, stream>>>(dists, ldbuf);
  k_mlh <<<19200, 256, 0, stream>>>(ldbuf, h_all, mlh_h);
  k_gemm_bt<<<dim3(100, 1), 256, 0, stream>>>(mlh_h, swp, s1h, sbp, 128, 384, 384, 2);
  k_gemm_bt<<<dim3(100, 3), 256, 0, stream>>>(s1h, rwp2, theme, rescale_b, 384, 128, 128, 3);
  k_gemm_conv<<<dim3(100, 3, 2), 256, 0, stream>>>(ldbuf, h_all, Wc2, convbuf);
  k_rnn <<<19200, 256, 0, stream>>>(theme, convbuf, conv_b, h_all, rnn);
  // phase 4: out = rnn @ out_w^T + out_b   (K split 40 ways: 480 = 15*32, exact)
  k_gemm_bt<<<dim3(2, 1, ZSPLIT), 256, 0, stream>>>(rnn, outw, opart, nullptr, 128, KO, KO / ZSPLIT, 0);
  k_red<<<128, 256, 0, stream>>>(opart, out_b, outp);
}

// Round 10
// 885.642 us; speedup vs baseline: 3.0555x; 1.0545x over previous
//
#include <hip/hip_runtime.h>
#include <math.h>

// ---------------- types ----------------
typedef _Float16 f16;
typedef _Float16 f16x8 __attribute__((ext_vector_type(8)));
typedef float f32x4 __attribute__((ext_vector_type(4)));
typedef unsigned int u32;
typedef u32 u32x4 __attribute__((ext_vector_type(4)));

#define DEV static __device__ __forceinline__

DEV float sigm(float x)  { return 1.0f / (1.0f + __expf(-x)); }
DEV float tanhfast(float x) { return 2.0f / (1.0f + __expf(-2.0f * x)) - 1.0f; }

// async global->LDS, 16B per lane (dest must be wave-uniform base + lane*16)
DEV void gld16(const void* g, void* l) {
  __builtin_amdgcn_global_load_lds((const __attribute__((address_space(1))) void*)g,
                                   (__attribute__((address_space(3))) void*)l, 16, 0, 0);
}

// init-only barrier (release/acquire) — used once before the t-loop
DEV void gbar(int* bar, int nblk) {
  __syncthreads();
  if (threadIdx.x == 0) {
    int* cnt = bar;
    int* gen = bar + 16;
    int g = __hip_atomic_load(gen, __ATOMIC_RELAXED, __HIP_MEMORY_SCOPE_AGENT);
    int a = __hip_atomic_fetch_add(cnt, 1, __ATOMIC_RELEASE, __HIP_MEMORY_SCOPE_AGENT);
    if (a == nblk - 1) {
      __hip_atomic_store(cnt, 0, __ATOMIC_RELAXED, __HIP_MEMORY_SCOPE_AGENT);
      __hip_atomic_store(gen, g + 1, __ATOMIC_RELEASE, __HIP_MEMORY_SCOPE_AGENT);
    } else {
      while (__hip_atomic_load(gen, __ATOMIC_RELAXED, __HIP_MEMORY_SCOPE_AGENT) == g)
        __builtin_amdgcn_s_sleep(1);
    }
    (void)__hip_atomic_load(gen, __ATOMIC_ACQUIRE, __HIP_MEMORY_SCOPE_AGENT);
  }
  __syncthreads();
}

// ---------------- problem constants ----------------
// B=256 V=50 N=32 D=128 H=384 L=12 CS=10 ND=4096 G=1560 OUT=128
#define GP 1664   // padded G (13*128) — XK gemm N and XKh row stride
#define KH 3840   // H*CS (conv gemm K)
#define KO 19200  // V*H  (out gemm K)
#define ZSPLIT 40 // out gemm K-split (19200/40 = 480 = 15*32, exact)
#define NGRP 16
#define NMEM 12
#define NBLK 192
#define XOLS 164  // xo local (LDS) row stride in f32
// Wl 10 tiles + xol 16x164 f32 + hl staging 512 f16
#define RECUR_LDS (122880 + 10496 + 1024)

// ---------------- workspace layout (bytes) ----------------
static constexpr size_t OFF_OPART = 0;                       // out partials 40*32768*4 = 5.24MB
static constexpr size_t OFF_ZB    = 104857600 - 262144;      // zbuf f16 196608
static constexpr size_t OFF_WK    = 104857600;               // 13631488
static constexpr size_t OFF_XK    = OFF_WK + 13631488;       // XKh f16 42598400
// aliases of the XK region (XKh dead after k_recur):
static constexpr size_t OFF_MLH   = OFF_XK;                  // mlh_h f16 9830400
static constexpr size_t OFF_S1    = OFF_XK + 9830400;        // s1h f16 3276800
static constexpr size_t OFF_TH    = OFF_XK + 13107200;       // theme f32 19660800
static constexpr size_t OFF_CV    = OFF_XK + 32768000;       // conv partials 2x19660800 (ends +72089600)
static constexpr size_t OFF_SWP   = OFF_XK + 72089600;       // swp f16 98304 (> XKh end)
static constexpr size_t OFF_RWP2  = OFF_XK + 72187904;       // rwp2 f16 98304
static constexpr size_t OFF_SBP   = OFF_XK + 72286208;       // sbp f32 512
static constexpr size_t OFF_RW    = OFF_XK + 85196800;       // RWpack f16 1474560
static constexpr size_t OFF_SV    = OFF_RW + 1474560;        // Sv f32 6656 (pad 8192)
static constexpr size_t OFF_BAR   = OFF_SV + 8192;           // flags + init bar (32 KB)
static constexpr size_t OFF_BIASC = OFF_BAR + 32768;         // 8192
static constexpr size_t OFF_HALL  = OFF_BIASC + 8192;        // h_all f16 9830400
static constexpr size_t OFF_LD    = OFF_HALL + 9830400;      // 512000
static constexpr size_t OFF_WC2   = OFF_LD + 512000;         // 2949120
static constexpr size_t OFF_RNN   = OFF_WC2 + 2949120;       // 9830400
static constexpr size_t OFF_OUTW  = OFF_RNN + 9830400;       // 4915200
static constexpr size_t OFF_EH    = OFF_OUTW + 4915200;      // embed f16 2560256

// ---------------- kernels ----------------

// kernel_w (1560 x 4097) -> Wk_f16 (1664 x 4096, zero-padded rows); biasc = kb+rb (padded 1664)
// v2 (G13): 8 elems/thread, f16x8 stores (2B scalar stores were the bottleneck).
__global__ __launch_bounds__(256) void k_prep_wk(const float* __restrict__ kw,
                                                 const float* __restrict__ kb,
                                                 const float* __restrict__ rb,
                                                 f16* __restrict__ Wk,
                                                 float* __restrict__ biasc) {
  long i = (long)blockIdx.x * 256 + threadIdx.x;   // chunk of 8
  if (i < 1664L * 4096 / 8) {
    long base = i * 8;
    int nn = (int)(base >> 12);
    int k  = (int)(base & 4095);
    f16x8 o;
    if (nn < 1560) {
      const float* s = kw + (long)nn * 4097 + k;
#pragma unroll
      for (int e = 0; e < 8; ++e) o[e] = (f16)s[e];
    } else {
#pragma unroll
      for (int e = 0; e < 8; ++e) o[e] = (f16)0.0f;
    }
    *(f16x8*)(Wk + base) = o;
  }
  if (i < 1664) biasc[i] = (i < 1560) ? (kb[i] + rb[i]) : 0.0f;
}

// merged small prep: [0,180) rwpack+Sv+bar, [180,276) scale pack,
// [276,636) conv_w pack x8, [636,1236) out_w cvt x8, [1236,1549) embed cvt x8
__global__ __launch_bounds__(512) void k_prep_misc(const float* __restrict__ rw,
                                                   const float* __restrict__ kw,
                                                   const float* __restrict__ sw,
                                                   const float* __restrict__ sb,
                                                   const float* __restrict__ rw2,
                                                   const float* __restrict__ cw,
                                                   const float* __restrict__ ow,
                                                   const float* __restrict__ embed,
                                                   f16* __restrict__ RWp,
                                                   float* __restrict__ Sv,
                                                   int* __restrict__ bar,
                                                   f16* __restrict__ swp,
                                                   float* __restrict__ sbp,
                                                   f16* __restrict__ rwp2,
                                                   f16* __restrict__ Wc2,
                                                   f16* __restrict__ outw,
                                                   f16* __restrict__ Eh) {
  const int blk = blockIdx.x, tid = threadIdx.x;
  if (blk < 180) {
    int i = blk * 512 + tid;                 // 92160 chunks of 8 halfs
    if (i < 92160) {
      int p = i / 7680;
      int rem = i - p * 7680;
      int tau = rem / 768;
      int r2 = rem - tau * 768;
      int f = r2 >> 6;
      int l = r2 & 63;
      int lc = tau * 16 + (l & 15);
      int n;
      if (lc < 24) n = lc;
      else if (lc < 32) n = -1;
      else { int run = (lc - 32) >> 5; n = 24 + (run * 12 + p) * 32 + ((lc - 32) & 31); }
      int k = f * 32 + ((l >> 4) << 3);
      f16x8 o;
      if (n >= 0) {
        const float* s = rw + (long)n * 385 + k;
#pragma unroll
        for (int e = 0; e < 8; ++e) o[e] = (f16)s[e];
      } else {
#pragma unroll
        for (int e = 0; e < 8; ++e) o[e] = (f16)0.0f;
      }
      *(f16x8*)(RWp + (long)i * 8) = o;
    }
    if (i < 1664)
      Sv[i] = (i < 1560) ? (rw[(long)i * 385 + 384] + kw[(long)i * 4097 + 4096]) : 0.0f;
    if (i < 8192) bar[i] = 0;
  } else if (blk < 276) {
    int i = (blk - 180) * 512 + tid;         // 49152
    if (i < 128 * 384) {
      int o = i / 384, k = i - o * 384;
      swp[i] = (f16)((o < 64) ? sw[o * 384 + k] : 0.0f);
      int o2 = i >> 7, k2 = i & 127;
      rwp2[i] = (f16)((k2 < 64) ? rw2[o2 * 64 + k2] : 0.0f);
    }
    if (i < 128) sbp[i] = (i < 64) ? sb[i] : 0.0f;
  } else if (blk < 636) {
    int i = (blk - 276) * 512 + tid;         // 184320 chunks of 8
    if (i < 184320) {
      int base = i * 8;
      int o = base / 3840;
      int c = base - o * 3840;
      int j = c / 384;
      int h = c - j * 384;                   // h multiple of 8 -> all 8 share o,j
      f16x8 v;
#pragma unroll
      for (int e = 0; e < 8; ++e) v[e] = (f16)cw[((long)o * 384 + h + e) * 10 + j];
      *(f16x8*)(Wc2 + base) = v;
    }
  } else if (blk < 1236) {
    long i = (long)(blk - 636) * 512 + tid;  // 307200 chunks of 8
    if (i < 307200) {
      long base = i * 8;                     // 32B-aligned
      float4 a = *(const float4*)(ow + base);
      float4 b2 = *(const float4*)(ow + base + 4);
      f16x8 v;
      v[0] = (f16)a.x;  v[1] = (f16)a.y;  v[2] = (f16)a.z;  v[3] = (f16)a.w;
      v[4] = (f16)b2.x; v[5] = (f16)b2.y; v[6] = (f16)b2.z; v[7] = (f16)b2.w;
      *(f16x8*)(outw + base) = v;
    }
  } else {
    long i = (long)(blk - 1236) * 512 + tid; // 160016 chunks of 8
    if (i < 160016) {
      long base = i * 8;
      float4 a = *(const float4*)(embed + base);
      float4 b2 = *(const float4*)(embed + base + 4);
      f16x8 v;
      v[0] = (f16)a.x;  v[1] = (f16)a.y;  v[2] = (f16)a.z;  v[3] = (f16)a.w;
      v[4] = (f16)b2.x; v[5] = (f16)b2.y; v[6] = (f16)b2.z; v[7] = (f16)b2.w;
      *(f16x8*)(Eh + base) = v;
    }
  }
}

// XKh = f16( gather(embed_h, ids) @ Wk^T + biasc ).
// v5: 256x128 tile, BK=64 dual-subtile staging, bijective XCD chunk map.
__global__ __launch_bounds__(256, 2) void k_gemm_emb(const int* __restrict__ ids,  // (12800,32)
                                                     const f16* __restrict__ Eh,  // (10001,128)
                                                     const f16* __restrict__ W,   // (1664,4096)
                                                     f16* __restrict__ C,         // (12800,GP)
                                                     const float* __restrict__ bias) {
  __shared__ __align__(16) f16 As0[256 * 32];
  __shared__ __align__(16) f16 As1[256 * 32];
  __shared__ __align__(16) f16 Bs0[128 * 32];
  __shared__ __align__(16) f16 Bs1[128 * 32];
  const int tid = threadIdx.x;
  // nwg = 50*13 = 650; q = 81, r = 2 — bijective XCD chunk map (m204)
  const int W0  = blockIdx.y * 50 + blockIdx.x;
  const int xcd = W0 & 7, idx = W0 >> 3;
  const int nw  = (xcd < 2) ? (xcd * 82 + idx) : (164 + (xcd - 2) * 81 + idx);
  const int bx  = nw % 50, by = nw / 50;
  const long rowA0 = (long)bx * 256;
  const long rowB0 = (long)by * 128;
  const int w = tid >> 6, lane = tid & 63;
  const int q = lane >> 4, r16 = lane & 15;
  f32x4 acc[4][8] = {};
  const int srow = tid >> 2;
  const int scol = (tid & 3) * 8;
  const int* idr0 = ids + (rowA0 + srow) * 32;
  const int* idr1 = idr0 + 64 * 32;
  const int* idr2 = idr0 + 128 * 32;
  const int* idr3 = idr0 + 192 * 32;
  const f16* gB0 = W + (rowB0 + srow) * 4096L + scol;
  const f16* gB1 = gB0 + 64L * 4096;
  f16* lA0 = As0 + tid * 8;
  f16* lA1 = As1 + tid * 8;
  f16* lB0 = Bs0 + tid * 8;
  f16* lB1 = Bs1 + tid * 8;
  int cur0 = idr0[0], cur1 = idr1[0], cur2 = idr2[0], cur3 = idr3[0];
  for (int n = 0; n < 32; ++n) {
    // prefetch next group's ids — 2 barrier-pairs of slack before use
    int nx0 = 0, nx1 = 0, nx2 = 0, nx3 = 0;
    if (n < 31) { nx0 = idr0[n + 1]; nx1 = idr1[n + 1]; nx2 = idr2[n + 1]; nx3 = idr3[n + 1]; }
#pragma unroll
    for (int kk = 0; kk < 2; ++kk) {
      const int k0 = n * 128 + kk * 64;
      const int d = kk * 64 + scol;
      __syncthreads();
      gld16(Eh + (size_t)cur0 * 128 + d,      lA0);
      gld16(Eh + (size_t)cur1 * 128 + d,      lA0 + 2048);
      gld16(Eh + (size_t)cur2 * 128 + d,      lA0 + 4096);
      gld16(Eh + (size_t)cur3 * 128 + d,      lA0 + 6144);
      gld16(Eh + (size_t)cur0 * 128 + d + 32, lA1);
      gld16(Eh + (size_t)cur1 * 128 + d + 32, lA1 + 2048);
      gld16(Eh + (size_t)cur2 * 128 + d + 32, lA1 + 4096);
      gld16(Eh + (size_t)cur3 * 128 + d + 32, lA1 + 6144);
      gld16(gB0 + k0,      lB0);
      gld16(gB1 + k0,      lB0 + 2048);
      gld16(gB0 + k0 + 32, lB1);
      gld16(gB1 + k0 + 32, lB1 + 2048);
      __syncthreads();
      f16x8 af[4], bf[8];
#pragma unroll
      for (int i = 0; i < 4; i++)
        af[i] = *(const f16x8*)&As0[(w * 64 + i * 16 + r16) * 32 + q * 8];
#pragma unroll
      for (int j = 0; j < 8; j++)
        bf[j] = *(const f16x8*)&Bs0[(j * 16 + r16) * 32 + q * 8];
#pragma unroll
      for (int i = 0; i < 4; i++)
#pragma unroll
        for (int j = 0; j < 8; j++)
          acc[i][j] = __builtin_amdgcn_mfma_f32_16x16x32_f16(af[i], bf[j], acc[i][j], 0, 0, 0);
#pragma unroll
      for (int i = 0; i < 4; i++)
        af[i] = *(const f16x8*)&As1[(w * 64 + i * 16 + r16) * 32 + q * 8];
#pragma unroll
      for (int j = 0; j < 8; j++)
        bf[j] = *(const f16x8*)&Bs1[(j * 16 + r16) * 32 + q * 8];
#pragma unroll
      for (int i = 0; i < 4; i++)
#pragma unroll
        for (int j = 0; j < 8; j++)
          acc[i][j] = __builtin_amdgcn_mfma_f32_16x16x32_f16(af[i], bf[j], acc[i][j], 0, 0, 0);
    }
    cur0 = nx0; cur1 = nx1; cur2 = nx2; cur3 = nx3;
  }
#pragma unroll
  for (int i = 0; i < 4; i++)
#pragma unroll
    for (int j = 0; j < 8; j++) {
      long row = rowA0 + w * 64 + i * 16 + q * 4;
      long col = rowB0 + j * 16 + r16;
      float bv = bias[col];
#pragma unroll
      for (int r = 0; r < 4; r++)
        C[(row + r) * (long)GP + col] = (f16)(acc[i][j][r] + bv);
    }
}

// conv GEMM with lh fused into A-staging
__global__ __launch_bounds__(256) void k_gemm_conv(const float* __restrict__ ld,   // (12800,10)
                                                   const f16* __restrict__ h_all, // (50,256,384)
                                                   const f16* __restrict__ W,     // Wc2 (384,3840)
                                                   float* __restrict__ C) {
  __shared__ __align__(16) f16 As[128 * 32];
  __shared__ __align__(16) f16 Bs[128 * 32];
  const int tid = threadIdx.x;
  const long rowA0 = (long)blockIdx.x * 128;
  const long rowB0 = (long)blockIdx.y * 128;
  const int ks = blockIdx.z * 1920;
  const long zoff = (long)blockIdx.z * (12800L * 384);
  const int w = tid >> 6, lane = tid & 63;
  const int q = lane >> 4, r16 = lane & 15;
  const int wr = w >> 1, wc = w & 1;
  f32x4 acc[4][4] = {};
  const int srow = tid >> 2;
  const int scol = (tid & 3) * 8;
  const int row0 = (int)rowA0 + srow, row1 = row0 + 64;
  const int b0r = row0 / 50, t0r = row0 - b0r * 50;
  const int b1r = row1 / 50, t1r = row1 - b1r * 50;
  const f16* gB0 = W + (rowB0 + srow) * (long)KH + ks + scol;
  const f16* gB1 = gB0 + 64L * KH;
  f16* lB = Bs + tid * 8;
  for (int k0 = 0; k0 < 1920; k0 += 32) {
    const int col0 = ks + k0;
    const int j = col0 / 384;
    const int hh = col0 - j * 384 + scol;
    const int s0 = t0r - 9 + j, s1 = t1r - 9 + j;
    __syncthreads();
    gld16(gB0 + k0, lB);
    gld16(gB1 + k0, lB + 2048);
    f16x8 a0v = {}, a1v = {};
    if (s0 >= 0) {
      const float lv = ld[row0 * 10 + j];
      f16x8 hv = *(const f16x8*)(h_all + ((size_t)s0 * 256 + b0r) * 384 + hh);
#pragma unroll
      for (int e = 0; e < 8; ++e) a0v[e] = (f16)((float)hv[e] * lv);
    }
    if (s1 >= 0) {
      const float lv = ld[row1 * 10 + j];
      f16x8 hv = *(const f16x8*)(h_all + ((size_t)s1 * 256 + b1r) * 384 + hh);
#pragma unroll
      for (int e = 0; e < 8; ++e) a1v[e] = (f16)((float)hv[e] * lv);
    }
    *(f16x8*)&As[srow * 32 + scol] = a0v;
    *(f16x8*)&As[(srow + 64) * 32 + scol] = a1v;
    __syncthreads();
    f16x8 af[4], bfr[4];
#pragma unroll
    for (int i = 0; i < 4; i++) {
      af[i]  = *(const f16x8*)&As[(wr * 64 + i * 16 + r16) * 32 + q * 8];
      bfr[i] = *(const f16x8*)&Bs[(wc * 64 + i * 16 + r16) * 32 + q * 8];
    }
#pragma unroll
    for (int i = 0; i < 4; i++)
#pragma unroll
      for (int j2 = 0; j2 < 4; j2++)
        acc[i][j2] = __builtin_amdgcn_mfma_f32_16x16x32_f16(af[i], bfr[j2], acc[i][j2], 0, 0, 0);
  }
#pragma unroll
  for (int i = 0; i < 4; i++)
#pragma unroll
    for (int j2 = 0; j2 < 4; j2++) {
      long row = rowA0 + wr * 64 + i * 16 + q * 4;
      long col = rowB0 + wc * 64 + j2 * 16 + r16;
#pragma unroll
      for (int r = 0; r < 4; r++)
        C[(row + r) * 384L + col + zoff] = acc[i][j2][r];
    }
}

// C = A(M x K) * W(N x K)^T (+bias[col]); m97-style global_load_lds staging.
__global__ __launch_bounds__(256) void k_gemm_bt(const f16* __restrict__ A,
                                                 const f16* __restrict__ W,
                                                 void* __restrict__ Cv,
                                                 const float* __restrict__ bias,
                                                 int N, int K, int kLen, int act) {
  __shared__ __align__(16) f16 As[128 * 32];
  __shared__ __align__(16) f16 Bs[128 * 32];
  const int tid = threadIdx.x;
  const long rowA0 = (long)blockIdx.x * 128;
  const long rowB0 = (long)blockIdx.y * 128;
  const long ks = (long)blockIdx.z * kLen;
  const long zoff = (long)blockIdx.z * ((long)gridDim.x * 128 * N);
  const int w = tid >> 6, lane = tid & 63;
  const int q = lane >> 4, r16 = lane & 15;
  const int wr = w >> 1, wc = w & 1;
  f32x4 acc[4][4] = {};
  const int srow = tid >> 2;
  const int scol = (tid & 3) * 8;
  const f16* gA0 = A + (rowA0 + srow) * (long)K + ks + scol;
  const f16* gA1 = gA0 + 64L * K;
  const f16* gB0 = W + (rowB0 + srow) * (long)K + ks + scol;
  const f16* gB1 = gB0 + 64L * K;
  f16* lA = As + tid * 8;
  f16* lB = Bs + tid * 8;
  for (int k0 = 0; k0 < kLen; k0 += 32) {
    __syncthreads();
    gld16(gA0 + k0, lA);
    gld16(gA1 + k0, lA + 2048);
    gld16(gB0 + k0, lB);
    gld16(gB1 + k0, lB + 2048);
    __syncthreads();
    f16x8 af[4], bfr[4];
#pragma unroll
    for (int i = 0; i < 4; i++) {
      af[i]  = *(const f16x8*)&As[(wr * 64 + i * 16 + r16) * 32 + q * 8];
      bfr[i] = *(const f16x8*)&Bs[(wc * 64 + i * 16 + r16) * 32 + q * 8];
    }
#pragma unroll
    for (int i = 0; i < 4; i++)
#pragma unroll
      for (int j = 0; j < 4; j++)
        acc[i][j] = __builtin_amdgcn_mfma_f32_16x16x32_f16(af[i], bfr[j], acc[i][j], 0, 0, 0);
  }
#pragma unroll
  for (int i = 0; i < 4; i++)
#pragma unroll
    for (int j = 0; j < 4; j++) {
      long row = rowA0 + wr * 64 + i * 16 + q * 4;
      long col = rowB0 + wc * 64 + j * 16 + r16;
      float bv = bias ? bias[col] : 0.0f;
#pragma unroll
      for (int r = 0; r < 4; r++) {
        float v = acc[i][j][r] + bv;
        long off = (row + r) * (long)N + col + zoff;
        if (act == 0)      ((float*)Cv)[off] = v;
        else if (act == 1) ((f16*)Cv)[off]   = (f16)v;
        else if (act == 2) ((f16*)Cv)[off]   = (f16)fmaxf(v, 0.0f);
        else               ((float*)Cv)[off] = sigm(v);
      }
    }
}

// gate-partitioned weights-stationary recurrence v4 (R1/R4/R6/R8-proven, 353 µs):
// 192 blocks = 16 groups x 12 members, 640 threads. h-exchange staged through
// LDS, wave 0 emits ONE coalesced global_store_dwordx4 sc0 sc1 (LLC-direct),
// drains (per-wave vmcnt => correct release), then raw flag store. Wave 1
// polls flags (overlaps wave 0's drain). LESSONS: (R5) do NOT distribute the
// poll across waves — agent-scope spin loops in 10 waves flooded the LLC
// (WRITE_SIZE 10MB->1.1GB). (R7) rec_w (1.28MB) can NOT be register-stationary
// on one CU — CU VGPR file = 2048 wave-regs total; the 12-member LDS split is
// the right partition.
__global__ __launch_bounds__(640)
void k_recur_coop(const f16* __restrict__ XKh,
                  const f16* __restrict__ RWp,
                  const float* __restrict__ Sv,
                  const float* __restrict__ timep,
                  f16* __restrict__ zbuf,
                  f16* __restrict__ hall,
                  float* __restrict__ dists,
                  int* __restrict__ bar) {
  extern __shared__ char smem[];
  f16*   Wl  = (f16*)smem;
  float* xol = (float*)(smem + 122880);
  f16*   hl  = (f16*)(smem + 122880 + 10496);   // 512 f16 h-staging
  const int tid = threadIdx.x;
  const int g = blockIdx.x / NMEM;
  const int m = blockIdx.x - g * NMEM;
  const int b0 = g * 16;
  int* gflags = bar + g * 256;
  int* ibar   = bar + 4096 + g * 32;
  const int w = tid >> 6, lane = tid & 63;
  const int q = lane >> 4, r16 = lane & 15;
  {
    const f16* src = RWp + (size_t)m * 61440;
    for (int i = tid; i < 7680; i += 640)
      *(f16x8*)(Wl + (size_t)i * 8) = *(const f16x8*)(src + (size_t)i * 8);
  }
  int ncol = -1; float Svc = 0.0f;
  if (w < 10) {
    const int lc = w * 16 + r16;
    if (lc < 24) ncol = lc;
    else if (lc >= 32) { int run = (lc - 32) >> 5; ncol = 24 + (run * 12 + m) * 32 + ((lc - 32) & 31); }
    if (ncol >= 0) Svc = Sv[ncol];
  }
  {
    f16x8 z = {};
    for (int i = m * 640 + tid; i < 768; i += NMEM * 640)
      *(f16x8*)(zbuf + (size_t)b0 * 384 + (size_t)i * 8) = z;
  }
  gbar(ibar, NMEM);

  const int ch = tid & 31, bloc = tid >> 5;
  float creg = 0.0f;
  f16 xkc[4] = {};
  if (w < 10 && ncol >= 0) {
#pragma unroll
    for (int r = 0; r < 4; ++r)
      xkc[r] = XKh[((long)(b0 + q * 4 + r) * 50) * GP + ncol];
  }

  for (int t = 0; t < 50; ++t) {
    const f16* hprev = (t == 0) ? zbuf : (hall + (size_t)(t - 1) * 98304);
    f16 xkn[4] = {};
    if (w < 10) {
      f16x8 af[12];
      const f16* ab = hprev + (size_t)(b0 + r16) * 384 + q * 8;
#pragma unroll
      for (int f = 0; f < 12; ++f) af[f] = *(const f16x8*)(ab + f * 32);
      if (t < 49 && ncol >= 0) {
#pragma unroll
        for (int r = 0; r < 4; ++r)
          xkn[r] = XKh[((long)(b0 + q * 4 + r) * 50 + (t + 1)) * GP + ncol];
      }
      float tv4[4];
#pragma unroll
      for (int r = 0; r < 4; ++r) tv4[r] = timep[(b0 + q * 4 + r) * 50 + t];
      const f16* bp = Wl + (size_t)w * 6144 + lane * 8;
      f32x4 a0 = {};
#pragma unroll
      for (int f = 0; f < 12; ++f)
        a0 = __builtin_amdgcn_mfma_f32_16x16x32_f16(af[f], *(const f16x8*)(bp + f * 512), a0, 0, 0, 0);
      const int lc = w * 16 + r16;
#pragma unroll
      for (int r = 0; r < 4; ++r)
        xol[(q * 4 + r) * XOLS + lc] = a0[r] + (float)xkc[r] + tv4[r] * Svc;
    }
    __syncthreads();
    if (bloc < 16) {
      const int gb = b0 + bloc;
      const float* xr = xol + bloc * XOLS;
      float e1[12], e2[12], mx1 = -1e30f, mx2 = -1e30f;
#pragma unroll
      for (int l = 0; l < 12; ++l) {
        e1[l] = xr[l];      mx1 = fmaxf(mx1, e1[l]);
        e2[l] = xr[12 + l]; mx2 = fmaxf(mx2, e2[l]);
      }
      float s1 = 0.0f, s2 = 0.0f;
#pragma unroll
      for (int l = 0; l < 12; ++l) {
        e1[l] = __expf(e1[l] - mx1); s1 += e1[l];
        e2[l] = __expf(e2[l] - mx2); s2 += e2[l];
      }
      float cum1 = 0.0f;
      for (int l = 0; l <= m; ++l) cum1 += e1[l];
      const float fmv = cum1 / s1;
      float cum2 = 0.0f;
      for (int l = 11; l >= m; --l) cum2 += e2[l];
      const float imv = cum2 / s2;
      if (m == 0 && ch == 0) {
        float ds = 0.0f;
#pragma unroll
        for (int l = 0; l < 12; ++l) ds += (float)(12 - l) * e1[l];
        dists[t * 256 + gb] = 1.0f - ds / (12.0f * s1);
      }
      const float fv = sigm(xr[32 + ch]);
      const float iv = sigm(xr[64 + ch]);
      const float og = sigm(xr[96 + ch]);
      const float ci = tanhfast(xr[128 + ch]);
      const float ov = fmv * imv;
      const float cn = ov * (fv * creg + iv * ci) + (fmv - ov) * creg + (imv - ov) * ci;
      creg = cn;
      const float hv = og * tanhfast(cn);
      hl[tid] = (f16)hv;    // stage to LDS; wave 0 emits one coalesced LLC store
    }
    __syncthreads();
    if (w == 0) {
      // lane l: row (l>>2) of the 16-batch slice, 16B chunk (l&3) of 64B —
      // one wave64 dwordx4 store covers the full 1 KB member h-slice.
      f32x4 d = *(const f32x4*)(hl + lane * 8);
      f16* dst = hall + ((size_t)t * 256 + b0 + (lane >> 2)) * 384 + m * 32 + (lane & 3) * 8;
      asm volatile("global_store_dwordx4 %0, %1, off sc0 sc1\n\t"
                   "s_waitcnt vmcnt(0)"
                   :: "v"(dst), "v"(d) : "memory");
      if (lane == 0) {
        int* fp = gflags + m * 16;
        int fv2 = t + 1;
        asm volatile("global_store_dword %0, %1, off sc0 sc1"
                     :: "v"(fp), "v"(fv2) : "memory");
      }
    }
    if (w == 1 && lane < NMEM) {
      while (__hip_atomic_load(gflags + lane * 16, __ATOMIC_RELAXED, __HIP_MEMORY_SCOPE_AGENT) < t + 1)
        __builtin_amdgcn_s_sleep(1);
    }
    __syncthreads();
    asm volatile("" ::: "memory");
#pragma unroll
    for (int r = 0; r < 4; ++r) xkc[r] = xkn[r];
  }
}

// ld[b,t,:] = softmax_j(cumsum_j dist[t-9+j])
__global__ __launch_bounds__(256) void k_ld(const float* __restrict__ dists,
                                            float* __restrict__ ld) {
  int i = blockIdx.x * 256 + threadIdx.x;
  if (i >= 12800) return;
  int b = i / 50, t = i - b * 50;
  float v[10];
  float cum = 0.0f, mx = -1e30f;
#pragma unroll
  for (int j = 0; j < 10; j++) {
    int s = t - 9 + j;
    float d = (s >= 0) ? dists[s * 256 + b] : 0.0f;
    cum += d; v[j] = cum; mx = fmaxf(mx, cum);
  }
  float sum = 0.0f;
#pragma unroll
  for (int j = 0; j < 10; j++) { v[j] = __expf(v[j] - mx); sum += v[j]; }
  float inv = 1.0f / sum;
#pragma unroll
  for (int j = 0; j < 10; j++) ld[i * 10 + j] = v[j] * inv;
}

// mlh_h[(b,t)][h] = mean_j ld*h
// v2 (G13): 8 channels/thread, f16x8 h_all loads + f16x8 store (was scalar f16
// loads — 98MB of h_all traffic at scalar rate was ~2x slower).
__global__ __launch_bounds__(256) void k_mlh(const float* __restrict__ ld,
                                             const f16* __restrict__ h_all,
                                             f16* __restrict__ mlh) {
  int idx = blockIdx.x * 256 + threadIdx.x;   // 12800*48 = 614400 chunks
  if (idx >= 614400) return;
  int row = idx / 48, hc = (idx - row * 48) * 8;
  int b = row / 50, t = row - b * 50;
  float acc[8] = {};
#pragma unroll
  for (int j = 0; j < 10; j++) {
    int s = t - 9 + j;
    if (s >= 0) {
      float lv = ld[row * 10 + j];
      f16x8 hv = *(const f16x8*)(h_all + ((size_t)s * 256 + b) * 384 + hc);
#pragma unroll
      for (int e = 0; e < 8; ++e) acc[e] += lv * (float)hv[e];
    }
  }
  f16x8 o;
#pragma unroll
  for (int e = 0; e < 8; ++e) o[e] = (f16)(acc[e] * 0.1f);
  *(f16x8*)(mlh + (size_t)row * 384 + hc) = o;
}

// rnn_f16[b][t*384+h] = theme*(conv0+conv1+conv_b) + h
// v2 (G13): 8 channels/thread, float4 convp/theme loads + f16x8 h/store.
__global__ __launch_bounds__(256) void k_rnn(const float* __restrict__ theme,
                                             const float* __restrict__ convp,
                                             const float* __restrict__ cb,
                                             const f16* __restrict__ h_all,
                                             f16* __restrict__ rnn) {
  int idx = blockIdx.x * 256 + threadIdx.x;   // 614400 chunks
  if (idx >= 614400) return;
  int row = idx / 48, hc = (idx - row * 48) * 8;
  int b = row / 50, t = row - b * 50;
  size_t base = (size_t)row * 384 + hc;       // 32B-aligned for f32
  float4 c0 = *(const float4*)(convp + base);
  float4 c1 = *(const float4*)(convp + base + 4);
  float4 d0 = *(const float4*)(convp + 4915200 + base);
  float4 d1 = *(const float4*)(convp + 4915200 + base + 4);
  float4 t0 = *(const float4*)(theme + base);
  float4 t1 = *(const float4*)(theme + base + 4);
  f16x8 hv = *(const f16x8*)(h_all + ((size_t)t * 256 + b) * 384 + hc);
  f16x8 o;
  o[0] = (f16)(t0.x * (c0.x + d0.x + cb[hc + 0]) + (float)hv[0]);
  o[1] = (f16)(t0.y * (c0.y + d0.y + cb[hc + 1]) + (float)hv[1]);
  o[2] = (f16)(t0.z * (c0.z + d0.z + cb[hc + 2]) + (float)hv[2]);
  o[3] = (f16)(t0.w * (c0.w + d0.w + cb[hc + 3]) + (float)hv[3]);
  o[4] = (f16)(t1.x * (c1.x + d1.x + cb[hc + 4]) + (float)hv[4]);
  o[5] = (f16)(t1.y * (c1.y + d1.y + cb[hc + 5]) + (float)hv[5]);
  o[6] = (f16)(t1.z * (c1.z + d1.z + cb[hc + 6]) + (float)hv[6]);
  o[7] = (f16)(t1.w * (c1.w + d1.w + cb[hc + 7]) + (float)hv[7]);
  *(f16x8*)(rnn + base) = o;
}

// out[i] = sum_z part[z][i] + out_b
__global__ __launch_bounds__(256) void k_red(const float* __restrict__ part,
                                             const float* __restrict__ ob,
                                             float* __restrict__ out) {
  int i = blockIdx.x * 256 + threadIdx.x;   // 32768
  float s = 0.0f;
#pragma unroll
  for (int z = 0; z < ZSPLIT; z++) s += part[z * 32768 + i];
  out[i] = s + ob[i & 127];
}

// ---------------- launch ----------------
extern "C" void kernel_launch(void* const* d_in, const int* in_sizes, int n_in,
                              void* d_out, int out_size, void* d_ws, size_t ws_size,
                              hipStream_t stream) {
  (void)in_sizes; (void)n_in; (void)out_size; (void)ws_size;
  const int*   node_ids  = (const int*)  d_in[0];
  const float* timep     = (const float*)d_in[3];
  const float* embed     = (const float*)d_in[6];
  const float* kernel_w  = (const float*)d_in[7];
  const float* kernel_b  = (const float*)d_in[8];
  const float* rec_w     = (const float*)d_in[9];
  const float* rec_b     = (const float*)d_in[10];
  const float* scale_w   = (const float*)d_in[11];
  const float* scale_b   = (const float*)d_in[12];
  const float* rescale_w = (const float*)d_in[13];
  const float* rescale_b = (const float*)d_in[14];
  const float* conv_w    = (const float*)d_in[15];
  const float* conv_b    = (const float*)d_in[16];
  const float* out_w     = (const float*)d_in[17];
  const float* out_b     = (const float*)d_in[18];

  char* ws = (char*)d_ws;
  float* opart   = (float*)(ws + OFF_OPART);
  f16*   zbuf    = (f16*)  (ws + OFF_ZB);
  f16*   Wk      = (f16*)  (ws + OFF_WK);
  f16*   XKh     = (f16*)  (ws + OFF_XK);
  f16*   mlh_h   = (f16*)  (ws + OFF_MLH);
  f16*   s1h     = (f16*)  (ws + OFF_S1);
  float* theme   = (float*)(ws + OFF_TH);
  float* convbuf = (float*)(ws + OFF_CV);
  f16*   swp     = (f16*)  (ws + OFF_SWP);
  f16*   rwp2    = (f16*)  (ws + OFF_RWP2);
  float* sbp     = (float*)(ws + OFF_SBP);
  f16*   RWp     = (f16*)  (ws + OFF_RW);
  float* Sv      = (float*)(ws + OFF_SV);
  int*   bar     = (int*)  (ws + OFF_BAR);
  float* biasc   = (float*)(ws + OFF_BIASC);
  f16*   h_all   = (f16*)  (ws + OFF_HALL);
  float* ldbuf   = (float*)(ws + OFF_LD);
  f16*   Wc2     = (f16*)  (ws + OFF_WC2);
  f16*   rnn     = (f16*)  (ws + OFF_RNN);
  f16*   outw    = (f16*)  (ws + OFF_OUTW);
  f16*   Eh      = (f16*)  (ws + OFF_EH);

  float* outp  = (float*)d_out;          // (256,128)
  float* dists = outp + 256 * 128;       // (50,256)

  // phase 0: prep (vectorized x8)
  k_prep_wk  <<<3332, 256, 0, stream>>>(kernel_w, kernel_b, rec_b, Wk, biasc);
  k_prep_misc<<<1549, 512, 0, stream>>>(rec_w, kernel_w, scale_w, scale_b, rescale_w,
                                        conv_w, out_w, embed,
                                        RWp, Sv, bar, swp, sbp, rwp2, Wc2, outw, Eh);
  // phase 1: XKh GEMM with fused embedding gather (256x128 tile, BK=64)
  k_gemm_emb<<<dim3(50, 13), 256, 0, stream>>>(node_ids, Eh, Wk, XKh, biasc);
  // phase 2: recurrence
  {
    hipFuncSetAttribute((const void*)k_recur_coop,
                        hipFuncAttributeMaxDynamicSharedMemorySize, RECUR_LDS);
    void* cargs[] = {(void*)&XKh, (void*)&RWp, (void*)&Sv, (void*)&timep,
                     (void*)&zbuf, (void*)&h_all, (void*)&dists, (void*)&bar};
    hipLaunchCooperativeKernel((void*)k_recur_coop, dim3(NBLK), dim3(640),
                               cargs, RECUR_LDS, stream);
  }
  // phase 3: deferred outputs (lh fused into conv GEMM staging)
  k_ld  <<<50,   256, 0, stream>>>(dists, ldbuf);
  k_mlh <<<2400, 256, 0, stream>>>(ldbuf, h_all, mlh_h);
  k_gemm_bt<<<dim3(100, 1), 256, 0, stream>>>(mlh_h, swp, s1h, sbp, 128, 384, 384, 2);
  k_gemm_bt<<<dim3(100, 3), 256, 0, stream>>>(s1h, rwp2, theme, rescale_b, 384, 128, 128, 3);
  k_gemm_conv<<<dim3(100, 3, 2), 256, 0, stream>>>(ldbuf, h_all, Wc2, convbuf);
  k_rnn <<<2400, 256, 0, stream>>>(theme, convbuf, conv_b, h_all, rnn);
  // phase 4: out = rnn @ out_w^T + out_b   (K split 40 ways: 480 = 15*32, exact)
  k_gemm_bt<<<dim3(2, 1, ZSPLIT), 256, 0, stream>>>(rnn, outw, opart, nullptr, 128, KO, KO / ZSPLIT, 0);
  k_red<<<128, 256, 0, stream>>>(opart, out_b, outp);
}